// Round 4
// baseline (332.115 us; speedup 1.0000x reference)
//
#include <hip/hip_runtime.h>
#include <math.h>

#define N 4096
#define E 32
#define NBLK 12
#define D_IN 2240
#define H1 256
#define H2 32
#define NOUT 51
#define MT 16
#define NPAD (N + E*(MT-1))   // 4576
#define NTILE (NPAD/MT)       // 286
#define KSPLIT 4
#define NROWS 4608
#define GMAX 96
#define NCONVBLK (35*4*E)     // 4480

typedef short s8v __attribute__((ext_vector_type(8)));
typedef float f4v __attribute__((ext_vector_type(4)));

__device__ __forceinline__ float gelu(float x){
    return 0.5f * x * (1.0f + erff(x * 0.70710678118654752f));
}
__device__ __forceinline__ unsigned short f2bf(float f){
    unsigned int u = __float_as_uint(f);
    unsigned int r = (u + 0x7fffu + ((u >> 16) & 1u)) >> 16;
    return (unsigned short)r;
}
__device__ __forceinline__ float bflo(unsigned int u){ return __uint_as_float(u << 16); }
__device__ __forceinline__ float bfhi(unsigned int u){ return __uint_as_float(u & 0xffff0000u); }

// --- DPP rotation-butterfly reduction over each 32-lane half (sum) ---
template<int CTRL>
__device__ __forceinline__ float dppadd(float x){
    int y = __builtin_amdgcn_update_dpp(0, __float_as_int(x), CTRL, 0xF, 0xF, true);
    return x + __int_as_float(y);
}
__device__ __forceinline__ float red32(float x){
    x = dppadd<0x121>(x);   // row_ror:1
    x = dppadd<0x122>(x);   // row_ror:2
    x = dppadd<0x124>(x);   // row_ror:4
    x = dppadd<0x128>(x);   // row_ror:8  -> each 16-group holds its sum
    int y = __builtin_amdgcn_ds_swizzle(__float_as_int(x), 0x401F);  // xor16
    return x + __int_as_float(y);
}

// ---------------- sort rows by expert + build 8-tile groups ----------------
__global__ void k_sort(const int* __restrict__ desc,
                       int* __restrict__ perm, int* __restrict__ tile_e,
                       int4* __restrict__ garr, int* __restrict__ ngroups){
    __shared__ int scnt[E];
    __shared__ int spoff[E+1];
    __shared__ int scur[E];
    int tid = threadIdx.x;
    if (tid < E) scnt[tid] = 0;
    __syncthreads();
    for (int n = tid; n < N; n += blockDim.x) atomicAdd(&scnt[desc[n]], 1);
    __syncthreads();
    if (tid == 0){
        int run = 0;
        for (int e = 0; e < E; e++){ spoff[e] = run; run += ((scnt[e] + MT - 1)/MT)*MT; }
        spoff[E] = run;
        int ng = 0;
        for (int e = 0; e < E; e++){
            int t0 = spoff[e]/MT, t1 = spoff[e+1]/MT;
            for (int t = t0; t < t1; t += 8){
                int nv = t1 - t; if (nv > 8) nv = 8;
                if (ng < GMAX) garr[ng] = make_int4(t, e, nv, 0);
                ng++;
            }
        }
        *ngroups = (ng > GMAX) ? GMAX : ng;
    }
    __syncthreads();
    if (tid < E) scur[tid] = spoff[tid];
    for (int p = tid; p < NPAD; p += blockDim.x) perm[p] = -1;
    __syncthreads();
    for (int n = tid; n < N; n += blockDim.x){
        int p = atomicAdd(&scur[desc[n]], 1);
        perm[p] = n;
    }
    for (int t = tid; t < NTILE; t += blockDim.x){
        int p0 = t*MT;
        int e = -1;
        if (p0 < spoff[E]){
            for (int q = 0; q < E; q++){
                if (p0 >= spoff[q] && p0 < spoff[q+1]){ e = q; break; }
            }
        }
        tile_e[t] = e;
    }
}

// -------- merged: build feature vectors (blocks 0..NPAD-1) + convert fc1_w (rest) --------
__global__ void k_prep(const int* __restrict__ perm,
                       const int* __restrict__ piece_idx,
                       const int* __restrict__ side_flag,
                       const int* __restrict__ ep_file,
                       const float* __restrict__ castle_ms,
                       const float* __restrict__ fifty_a,
                       const int* __restrict__ desc_idx,
                       const float* __restrict__ Wp_w, const float* __restrict__ Wp_b,
                       const float* __restrict__ Wc_w, const float* __restrict__ Wc_b,
                       const float* __restrict__ Wep_w, const float* __restrict__ Wep_b,
                       const float* __restrict__ Wf_w, const float* __restrict__ Wf_b,
                       unsigned short* __restrict__ xs,
                       const float* __restrict__ W1, unsigned short* __restrict__ Wt){
    __shared__ float lds[64][65];
    int tid = threadIdx.x;
    if (blockIdx.x >= NPAD){
        int b = blockIdx.x - NPAD;
        int kt = b % 35;
        int nt = (b / 35) & 3;
        int e  = b / 140;
        int k0 = kt*64, n0 = nt*64;
        int kk = tid >> 4, nn = (tid & 15) * 4;
        const float* src = W1 + ((size_t)e*D_IN + k0)*H1 + n0;
        #pragma unroll
        for (int r = 0; r < 4; r++){
            float4 v = *(const float4*)(src + (size_t)(kk + r*16)*H1 + nn);
            lds[kk + r*16][nn]   = v.x;
            lds[kk + r*16][nn+1] = v.y;
            lds[kk + r*16][nn+2] = v.z;
            lds[kk + r*16][nn+3] = v.w;
        }
        __syncthreads();
        int n = tid >> 2, kq = tid & 3;
        s8v p0, p1;
        #pragma unroll
        for (int j = 0; j < 8; j++) p0[j] = (short)f2bf(lds[kq*16 + j][n]);
        #pragma unroll
        for (int j = 0; j < 8; j++) p1[j] = (short)f2bf(lds[kq*16 + 8 + j][n]);
        unsigned short* dst = Wt + ((size_t)(e*H1 + n0 + n))*D_IN + k0 + kq*16;
        *(s8v*)dst       = p0;
        *(s8v*)(dst + 8) = p1;
        return;
    }
    int pos = blockIdx.x;
    int row = perm[pos];
    unsigned short* xr = xs + (size_t)pos * D_IN;
    if (row < 0){
        s8v z = {0,0,0,0,0,0,0,0};
        for (int t = tid; t < D_IN/8; t += blockDim.x) *(s8v*)(xr + t*8) = z;
        return;
    }
    int d = desc_idx[row];
    int s = side_flag[row];
    __shared__ int pidx[64];
    if (tid < 64) pidx[tid] = piece_idx[row*64 + tid];
    __syncthreads();
    const float* Wp  = s ? Wp_b  : Wp_w;
    const float* Wc  = s ? Wc_b  : Wc_w;
    const float* Wep = s ? Wep_b : Wep_w;
    const float* Wf  = s ? Wf_b  : Wf_w;
    int ep  = ep_file[row];
    int epc = ep > 0 ? ep : 0;
    float a = fifty_a[row];
    for (int t = tid; t < D_IN/8; t += blockDim.x){
        int i0 = t*8;
        float v[8];
        if (i0 < 2048){
            int sq = i0 >> 5, c0 = i0 & 31;
            int pc = pidx[sq];
            float msk = pc >= 0 ? 1.0f : 0.0f;
            int pcc = pc > 0 ? pc : 0;
            const float* base = Wp + (((size_t)d*64 + sq)*12 + pcc)*32 + c0;
            float4 a0 = *(const float4*)base;
            float4 a1 = *(const float4*)(base + 4);
            v[0]=a0.x*msk; v[1]=a0.y*msk; v[2]=a0.z*msk; v[3]=a0.w*msk;
            v[4]=a1.x*msk; v[5]=a1.y*msk; v[6]=a1.z*msk; v[7]=a1.w*msk;
        } else if (i0 < 2176){
            int j = i0 - 2048; int ci = j >> 5, c0 = j & 31;
            float cv = castle_ms[row*4 + ci];
            const float* base = Wc + ((size_t)d*4 + ci)*32 + c0;
            float4 a0 = *(const float4*)base;
            float4 a1 = *(const float4*)(base + 4);
            v[0]=a0.x*cv; v[1]=a0.y*cv; v[2]=a0.z*cv; v[3]=a0.w*cv;
            v[4]=a1.x*cv; v[5]=a1.y*cv; v[6]=a1.z*cv; v[7]=a1.w*cv;
        } else if (i0 < 2208){
            int c0 = i0 - 2176;
            float msk = ep >= 0 ? 1.0f : 0.0f;
            const float* base = Wep + ((size_t)d*8 + epc)*32 + c0;
            float4 a0 = *(const float4*)base;
            float4 a1 = *(const float4*)(base + 4);
            v[0]=a0.x*msk; v[1]=a0.y*msk; v[2]=a0.z*msk; v[3]=a0.w*msk;
            v[4]=a1.x*msk; v[5]=a1.y*msk; v[6]=a1.z*msk; v[7]=a1.w*msk;
        } else {
            int c0 = i0 - 2208;
            #pragma unroll
            for (int j = 0; j < 8; j++)
                v[j] = (1.0f - a) * Wf[(size_t)d*64 + c0 + j] + a * Wf[(size_t)d*64 + 32 + c0 + j];
        }
        s8v p;
        #pragma unroll
        for (int j = 0; j < 8; j++) p[j] = (short)f2bf(v[j]);
        *(s8v*)(xr + i0) = p;
    }
}

// ------- fc1 MFMA: groups of 128 rows x 256 cols, K split 4, partial f32 out -------
__launch_bounds__(256)
__global__ void k_fc1(const int4* __restrict__ garr, const int* __restrict__ ngroups,
                      const unsigned short* __restrict__ xs,
                      const unsigned short* __restrict__ Wt,
                      float* __restrict__ h1p){
    int g = blockIdx.x;
    if (g >= *ngroups) return;
    int4 gi = garr[g];
    int tile0 = gi.x, e = gi.y, nv = gi.z;
    int kc = blockIdx.y, nh = blockIdx.z;
    int kstart = (kc <= 2) ? kc*18 : 53;
    int nsteps = (kc < 2) ? 18 : 17;
    int lane = threadIdx.x & 63, wave = threadIdx.x >> 6;
    int quad = lane >> 4, l16 = lane & 15;
    int col0 = nh*128 + wave*32 + l16;
    const unsigned short* Ab = xs + (size_t)(tile0*MT + l16)*D_IN + quad*8;
    const unsigned short* B0 = Wt + ((size_t)e*H1 + col0)*D_IN + quad*8;
    const unsigned short* B1 = B0 + (size_t)16*D_IN;
    f4v acc[8][2];
    #pragma unroll
    for (int mt = 0; mt < 8; mt++){ acc[mt][0] = (f4v){0.f,0.f,0.f,0.f}; acc[mt][1] = (f4v){0.f,0.f,0.f,0.f}; }
    int kend = kstart + nsteps;
    #pragma unroll 2
    for (int s = kstart; s < kend; s++){
        int ko = s*32;
        s8v b0 = *(const s8v*)(B0 + ko);
        s8v b1 = *(const s8v*)(B1 + ko);
        #pragma unroll
        for (int mt = 0; mt < 8; mt++){
            s8v av = *(const s8v*)(Ab + (size_t)mt*MT*D_IN + ko);
            acc[mt][0] = __builtin_amdgcn_mfma_f32_16x16x32_bf16(av, b0, acc[mt][0], 0, 0, 0);
            acc[mt][1] = __builtin_amdgcn_mfma_f32_16x16x32_bf16(av, b1, acc[mt][1], 0, 0, 0);
        }
    }
    float* out = h1p + (size_t)kc*NROWS*H1;
    #pragma unroll
    for (int mt = 0; mt < 8; mt++){
        if (mt >= nv) break;
        int posb = (tile0 + mt)*MT + quad*4;
        #pragma unroll
        for (int r = 0; r < 4; r++){
            out[(size_t)(posb + r)*H1 + col0]      = acc[mt][0][r];
            out[(size_t)(posb + r)*H1 + col0 + 16] = acc[mt][1][r];
        }
    }
}

// ------- fused tail: 1024 threads, 1 row per wave, 2-way k-split per column -------
// launch_bounds (1024,4): round-3's (1024,8) forced VGPR<=32 -> scratch spills
// (WRITE_SIZE 978KB -> 5.3MB). Cap 128 removes spill; <=64 VGPRs still allows
// 2 blocks/CU (LDS-limited) for the doubled wave count.
__launch_bounds__(1024, 4)
__global__ void k_tail(const int* __restrict__ tile_e, const int* __restrict__ perm,
                       const float* __restrict__ h1p, const float* __restrict__ b1,
                       const float* __restrict__ g1, const float* __restrict__ be1,
                       const float* __restrict__ W2, const float* __restrict__ b2,
                       const float* __restrict__ g2, const float* __restrict__ be2,
                       const float* __restrict__ Aw, const float* __restrict__ Abv,
                       const float* __restrict__ Ag, const float* __restrict__ Abe,
                       const float* __restrict__ Bw, const float* __restrict__ Bb,
                       const float* __restrict__ Bg, const float* __restrict__ Bbe,
                       const float* __restrict__ Ow, const float* __restrict__ Ob,
                       const float* __restrict__ bins,
                       float* __restrict__ out){
    int t = blockIdx.x;
    int e = tile_e[t];
    if (e < 0) return;
    int tid = threadIdx.x;

    __shared__ __align__(16) unsigned int smem[12288];   // 48 KB union
    __shared__ __align__(16) float vecs[NBLK*6*32];      // 9 KB
    __shared__ __align__(16) float sh2[MT][36];
    __shared__ __align__(16) float sh3[MT][36];

    float* shf = (float*)smem;                 // [16][260] floats, phase 1
    unsigned int* W2pk = smem + 4160;          // 4096 u32, phase 1

    // ---- prefetch residual weights into registers (overlaps phase 1) ----
    // flat image identical to 512-thread version: flat[f], f = mi*512 + slot
    unsigned int wreg[12];
    {
        #pragma unroll
        for (int i = 0; i < 12; i++){
            int f = i*1024 + tid;
            int mi = f >> 9;             // matrix 0..23
            int slot = f & 511;
            int h = slot & 1, q = slot >> 1, cc = q & 31, p2 = q >> 5;
            int k0 = 4*p2 + 2*h;
            const float* src = (mi & 1) ? Bw : Aw;
            size_t base = ((size_t)(mi >> 1)*E + e)*1024;
            unsigned int lo = f2bf(src[base + k0*32 + cc]);
            unsigned int hi = f2bf(src[base + (k0+1)*32 + cc]);
            wreg[i] = lo | (hi << 16);
        }
    }
    // ---- phase 1a: W2 -> bf16 k-pair packed ----
    {
        const float* W2e = W2 + (size_t)e*H1*H2;
        for (int j = tid; j < 4096; j += 1024){
            int h = j & 1, q = j >> 1, cc = q & 31, p2 = q >> 5;
            int k0 = 4*p2 + 2*h;
            unsigned int lo = f2bf(W2e[k0*32 + cc]);
            unsigned int hi = f2bf(W2e[(k0+1)*32 + cc]);
            W2pk[(p2*32 + cc)*2 + h] = lo | (hi << 16);
        }
    }
    // ---- phase 1b: LN/bias vectors for all 12 blocks ----
    for (int j = tid; j < NBLK*6*32; j += 1024){
        int cc = j & 31, vi = (j >> 5) % 6, tb = j / 192;
        size_t wb = (size_t)tb*E + e;
        const float* src;
        switch(vi){ case 0: src=Abv; break; case 1: src=Ag; break; case 2: src=Abe; break;
                    case 3: src=Bb;  break; case 4: src=Bg; break; default: src=Bbe; }
        vecs[j] = src[wb*32 + cc];
    }
    // ---- phase 1c: sum fc1 K-partials + bias + gelu -> shf ----
    {
        int slot = tid;               // MT*64 == 1024 == blockDim
        int r = slot >> 6, c4 = (slot & 63) << 2;
        int row = t*MT + r;
        float4 v = {0.f,0.f,0.f,0.f};
        #pragma unroll
        for (int kc = 0; kc < KSPLIT; kc++){
            float4 p = *(const float4*)(h1p + ((size_t)kc*NROWS + row)*H1 + c4);
            v.x += p.x; v.y += p.y; v.z += p.z; v.w += p.w;
        }
        float4 bb = *(const float4*)(b1 + e*H1 + c4);
        shf[r*260 + c4]   = gelu(v.x + bb.x);
        shf[r*260 + c4+1] = gelu(v.y + bb.y);
        shf[r*260 + c4+2] = gelu(v.z + bb.z);
        shf[r*260 + c4+3] = gelu(v.w + bb.w);
    }
    __syncthreads();

    int m = tid >> 6;            // one row per wave
    int lane = tid & 63;
    int c = lane & 31;           // column 0..31
    int half = lane >> 5;        // k-split half

    // ---- LN1 over 256 cols: each lane sums 4 cols, 64-lane reduce ----
    {
        float s = 0.f, s2 = 0.f;
        #pragma unroll
        for (int j = 0; j < 4; j++){
            float x = shf[m*260 + lane + 64*j];
            s += x; s2 += x*x;
        }
        s  = red32(s);  s  += __shfl_xor(s, 32);
        s2 = red32(s2); s2 += __shfl_xor(s2, 32);
        float mean = s * (1.0f/H1);
        float var  = s2 * (1.0f/H1) - mean*mean;
        float rs = rsqrtf(var + 1e-5f);
        #pragma unroll
        for (int j = 0; j < 4; j++){
            int k = lane + 64*j;
            shf[m*260 + k] = (shf[m*260 + k] - mean) * rs * g1[e*H1 + k] + be1[e*H1 + k];
        }
    }
    // ---- fc2 GEMV [256->32], 2-way k-split + gelu + LN2 ----
    float hv;
    {
        const uint2* W2p = (const uint2*)W2pk;
        float q0=0.f,q1=0.f,q2=0.f,q3=0.f;
        int p2b = half*32;
        #pragma unroll 8
        for (int p2i = 0; p2i < 32; p2i++){
            int p2 = p2b + p2i;
            uint2 w = W2p[p2*32 + c];
            float4 h4 = *(const float4*)(shf + m*260 + p2*4);
            q0 = fmaf(h4.x, bflo(w.x), q0);
            q1 = fmaf(h4.y, bfhi(w.x), q1);
            q2 = fmaf(h4.z, bflo(w.y), q2);
            q3 = fmaf(h4.w, bfhi(w.y), q3);
        }
        float acc = (q0+q1) + (q2+q3);
        acc += __shfl_xor(acc, 32);
        acc += b2[e*H2 + c];
        float y = gelu(acc);
        float s  = red32(y);
        float s2 = red32(y*y);
        float mean2 = s * (1.0f/H2);
        float var2  = s2 * (1.0f/H2) - mean2*mean2;
        hv = (y - mean2) * rsqrtf(var2 + 1e-5f) * g2[e*H2+c] + be2[e*H2+c];
    }
    __syncthreads();   // done with shf/W2pk

    // ---- phase 2: dump prefetched residual weights to LDS ----
    #pragma unroll
    for (int i = 0; i < 12; i++) smem[i*1024 + tid] = wreg[i];
    __syncthreads();

    // ---- 12 residual blocks: zero barriers, one-pass LN, 2-way k-split GEMVs ----
    for (int tb = 0; tb < NBLK; tb++){
        const float* vA = &vecs[tb*192];
        const uint2* WA = (const uint2*)(smem + (tb*2+0)*512);
        const uint2* WB = (const uint2*)(smem + (tb*2+1)*512);
        if (half == 0) sh2[m][c] = hv;
        float q0=0.f,q1=0.f,q2=0.f,q3=0.f;
        int p2b = half*4;
        #pragma unroll
        for (int p2i = 0; p2i < 4; p2i++){
            int p2 = p2b + p2i;
            uint2 w = WA[p2*32 + c];
            float4 h4 = *(const float4*)(&sh2[m][p2*4]);
            q0 = fmaf(h4.x, bflo(w.x), q0);
            q1 = fmaf(h4.y, bfhi(w.x), q1);
            q2 = fmaf(h4.z, bflo(w.y), q2);
            q3 = fmaf(h4.w, bfhi(w.y), q3);
        }
        float ya = (q0+q1) + (q2+q3);
        ya += __shfl_xor(ya, 32);
        ya += vA[c];
        ya = gelu(ya);
        float sa  = red32(ya);
        float sa2 = red32(ya*ya);
        float ma = sa * (1.0f/H2);
        float va = sa2 * (1.0f/H2) - ma*ma;
        float yA = (ya - ma) * rsqrtf(va + 1e-5f) * vA[32+c] + vA[64+c];
        if (half == 0) sh3[m][c] = yA;
        q0=0.f; q1=0.f; q2=0.f; q3=0.f;
        #pragma unroll
        for (int p2i = 0; p2i < 4; p2i++){
            int p2 = p2b + p2i;
            uint2 w = WB[p2*32 + c];
            float4 h4 = *(const float4*)(&sh3[m][p2*4]);
            q0 = fmaf(h4.x, bflo(w.x), q0);
            q1 = fmaf(h4.y, bfhi(w.x), q1);
            q2 = fmaf(h4.z, bflo(w.y), q2);
            q3 = fmaf(h4.w, bfhi(w.y), q3);
        }
        float yb = (q0+q1) + (q2+q3);
        yb += __shfl_xor(yb, 32);
        yb += vA[96+c];
        yb = gelu(yb);
        float sb  = red32(yb);
        float sb2 = red32(yb*yb);
        float mb = sb * (1.0f/H2);
        float vb = sb2 * (1.0f/H2) - mb*mb;
        hv += (yb - mb) * rsqrtf(vb + 1e-5f) * vA[128+c] + vA[160+c];
    }

    // ---- out-proj + softmax + p_win ----
    if (half == 0) sh2[m][c] = gelu(hv);
    __syncthreads();
    int wave = tid >> 6;
    const float* W = Ow + (size_t)e*32*NOUT;
    {
        int rr = wave;   // 16 waves, one row each
        int orow = perm[t*MT + rr];
        if (orow >= 0){
            float acc = (lane < NOUT) ? Ob[e*NOUT + lane] : -INFINITY;
            #pragma unroll
            for (int k = 0; k < 32; k++){
                float gk = sh2[rr][k];
                if (lane < NOUT) acc = fmaf(gk, W[k*NOUT + lane], acc);
            }
            if (lane < NOUT) out[(size_t)orow*NOUT + lane] = acc;
            float mx = acc;
            #pragma unroll
            for (int o = 32; o > 0; o >>= 1) mx = fmaxf(mx, __shfl_xor(mx, o));
            float pp = (lane < NOUT) ? expf(acc - mx) : 0.0f;
            float sum = pp;
            float pb = (lane < NOUT) ? pp * bins[lane] : 0.0f;
            float sb = pb;
            #pragma unroll
            for (int o = 32; o > 0; o >>= 1){ sum += __shfl_xor(sum, o); sb += __shfl_xor(sb, o); }
            if (lane == 0) out[(size_t)N*NOUT + orow] = sb / sum;
        }
    }
}

extern "C" void kernel_launch(void* const* d_in, const int* in_sizes, int n_in,
                              void* d_out, int out_size, void* d_ws, size_t ws_size,
                              hipStream_t stream){
    const int*   piece_idx = (const int*)d_in[0];
    const int*   side_flag = (const int*)d_in[1];
    const int*   ep_file   = (const int*)d_in[2];
    const float* castle_ms = (const float*)d_in[3];
    const float* fifty_a   = (const float*)d_in[4];
    const int*   desc      = (const int*)d_in[5];
    const float* Wp_w  = (const float*)d_in[6];
    const float* Wp_b  = (const float*)d_in[7];
    const float* Wc_w  = (const float*)d_in[8];
    const float* Wc_b  = (const float*)d_in[9];
    const float* Wep_w = (const float*)d_in[10];
    const float* Wep_b = (const float*)d_in[11];
    const float* Wf_w  = (const float*)d_in[12];
    const float* Wf_b  = (const float*)d_in[13];
    const float* fc1_w = (const float*)d_in[14];
    const float* fc1_b = (const float*)d_in[15];
    const float* ln1_g = (const float*)d_in[16];
    const float* ln1_b = (const float*)d_in[17];
    const float* fc2_w = (const float*)d_in[18];
    const float* fc2_b = (const float*)d_in[19];
    const float* ln2_g = (const float*)d_in[20];
    const float* ln2_b = (const float*)d_in[21];
    const float* blkA_w  = (const float*)d_in[22];
    const float* blkA_b  = (const float*)d_in[23];
    const float* blkA_g  = (const float*)d_in[24];
    const float* blkA_be = (const float*)d_in[25];
    const float* blkB_w  = (const float*)d_in[26];
    const float* blkB_b  = (const float*)d_in[27];
    const float* blkB_g  = (const float*)d_in[28];
    const float* blkB_be = (const float*)d_in[29];
    const float* out_w = (const float*)d_in[30];
    const float* out_b = (const float*)d_in[31];
    const float* bins  = (const float*)d_in[32];

    char* wsp = (char*)d_ws;
    auto alloc = [&](size_t bytes){ void* p = (void*)wsp; wsp += (bytes + 255) & ~(size_t)255; return p; };
    int*            perm    = (int*)            alloc((size_t)NPAD*4);
    int*            tile_e  = (int*)            alloc((size_t)NTILE*4);
    int4*           garr    = (int4*)           alloc((size_t)GMAX*16);
    int*            ngroups = (int*)            alloc(256);
    unsigned short* Wt      = (unsigned short*) alloc((size_t)E*H1*D_IN*2);
    unsigned short* xs      = (unsigned short*) alloc((size_t)(NPAD+128)*D_IN*2);
    float*          h1p     = (float*)          alloc((size_t)KSPLIT*NROWS*H1*4);

    k_sort<<<1, 256, 0, stream>>>(desc, perm, tile_e, garr, ngroups);
    k_prep<<<NPAD + NCONVBLK, 256, 0, stream>>>(perm, piece_idx, side_flag, ep_file,
                                                castle_ms, fifty_a, desc,
                                                Wp_w, Wp_b, Wc_w, Wc_b,
                                                Wep_w, Wep_b, Wf_w, Wf_b,
                                                xs, fc1_w, Wt);
    k_fc1<<<dim3(GMAX, KSPLIT, 2), 256, 0, stream>>>(garr, ngroups, xs, Wt, h1p);
    k_tail<<<NTILE, 1024, 0, stream>>>(tile_e, perm, h1p, fc1_b, ln1_g, ln1_b,
                                       fc2_w, fc2_b, ln2_g, ln2_b,
                                       blkA_w, blkA_b, blkA_g, blkA_be,
                                       blkB_w, blkB_b, blkB_g, blkB_be,
                                       out_w, out_b, bins, (float*)d_out);
}

// Round 6
// 300.558 us; speedup vs baseline: 1.1050x; 1.1050x over previous
//
#include <hip/hip_runtime.h>
#include <math.h>

#define N 4096
#define E 32
#define NBLK 12
#define D_IN 2240
#define H1 256
#define H2 32
#define NOUT 51
#define MT 16
#define NPAD (N + E*(MT-1))   // 4576
#define NTILE (NPAD/MT)       // 286
#define KSPLIT 4
#define NROWS 4608
#define GMAX 96
#define NCONVBLK (35*4*E)     // 4480

typedef short s8v __attribute__((ext_vector_type(8)));
typedef float f4v __attribute__((ext_vector_type(4)));

__device__ __forceinline__ float gelu(float x){
    return 0.5f * x * (1.0f + erff(x * 0.70710678118654752f));
}
__device__ __forceinline__ unsigned short f2bf(float f){
    unsigned int u = __float_as_uint(f);
    unsigned int r = (u + 0x7fffu + ((u >> 16) & 1u)) >> 16;
    return (unsigned short)r;
}
__device__ __forceinline__ float bflo(unsigned int u){ return __uint_as_float(u << 16); }
__device__ __forceinline__ float bfhi(unsigned int u){ return __uint_as_float(u & 0xffff0000u); }

// --- DPP rotation-butterfly reduction over each 32-lane half (sum) ---
template<int CTRL>
__device__ __forceinline__ float dppadd(float x){
    int y = __builtin_amdgcn_update_dpp(0, __float_as_int(x), CTRL, 0xF, 0xF, true);
    return x + __int_as_float(y);
}
__device__ __forceinline__ float red32(float x){
    x = dppadd<0x121>(x);   // row_ror:1
    x = dppadd<0x122>(x);   // row_ror:2
    x = dppadd<0x124>(x);   // row_ror:4
    x = dppadd<0x128>(x);   // row_ror:8  -> each 16-group holds its sum
    int y = __builtin_amdgcn_ds_swizzle(__float_as_int(x), 0x401F);  // xor16
    return x + __int_as_float(y);
}

// ---------------- sort rows by expert + build 8-tile groups ----------------
__global__ void k_sort(const int* __restrict__ desc,
                       int* __restrict__ perm, int* __restrict__ tile_e,
                       int4* __restrict__ garr, int* __restrict__ ngroups){
    __shared__ int scnt[E];
    __shared__ int spoff[E+1];
    __shared__ int scur[E];
    int tid = threadIdx.x;
    if (tid < E) scnt[tid] = 0;
    __syncthreads();
    for (int n = tid; n < N; n += blockDim.x) atomicAdd(&scnt[desc[n]], 1);
    __syncthreads();
    if (tid == 0){
        int run = 0;
        for (int e = 0; e < E; e++){ spoff[e] = run; run += ((scnt[e] + MT - 1)/MT)*MT; }
        spoff[E] = run;
        int ng = 0;
        for (int e = 0; e < E; e++){
            int t0 = spoff[e]/MT, t1 = spoff[e+1]/MT;
            for (int t = t0; t < t1; t += 8){
                int nv = t1 - t; if (nv > 8) nv = 8;
                if (ng < GMAX) garr[ng] = make_int4(t, e, nv, 0);
                ng++;
            }
        }
        *ngroups = (ng > GMAX) ? GMAX : ng;
    }
    __syncthreads();
    if (tid < E) scur[tid] = spoff[tid];
    for (int p = tid; p < NPAD; p += blockDim.x) perm[p] = -1;
    __syncthreads();
    for (int n = tid; n < N; n += blockDim.x){
        int p = atomicAdd(&scur[desc[n]], 1);
        perm[p] = n;
    }
    for (int t = tid; t < NTILE; t += blockDim.x){
        int p0 = t*MT;
        int e = -1;
        if (p0 < spoff[E]){
            for (int q = 0; q < E; q++){
                if (p0 >= spoff[q] && p0 < spoff[q+1]){ e = q; break; }
            }
        }
        tile_e[t] = e;
    }
}

// -------- merged: build feature vectors (blocks 0..NPAD-1) + convert fc1_w (rest) --------
__global__ void k_prep(const int* __restrict__ perm,
                       const int* __restrict__ piece_idx,
                       const int* __restrict__ side_flag,
                       const int* __restrict__ ep_file,
                       const float* __restrict__ castle_ms,
                       const float* __restrict__ fifty_a,
                       const int* __restrict__ desc_idx,
                       const float* __restrict__ Wp_w, const float* __restrict__ Wp_b,
                       const float* __restrict__ Wc_w, const float* __restrict__ Wc_b,
                       const float* __restrict__ Wep_w, const float* __restrict__ Wep_b,
                       const float* __restrict__ Wf_w, const float* __restrict__ Wf_b,
                       unsigned short* __restrict__ xs,
                       const float* __restrict__ W1, unsigned short* __restrict__ Wt){
    __shared__ float lds[64][65];
    int tid = threadIdx.x;
    if (blockIdx.x >= NPAD){
        int b = blockIdx.x - NPAD;
        int kt = b % 35;
        int nt = (b / 35) & 3;
        int e  = b / 140;
        int k0 = kt*64, n0 = nt*64;
        int kk = tid >> 4, nn = (tid & 15) * 4;
        const float* src = W1 + ((size_t)e*D_IN + k0)*H1 + n0;
        #pragma unroll
        for (int r = 0; r < 4; r++){
            float4 v = *(const float4*)(src + (size_t)(kk + r*16)*H1 + nn);
            lds[kk + r*16][nn]   = v.x;
            lds[kk + r*16][nn+1] = v.y;
            lds[kk + r*16][nn+2] = v.z;
            lds[kk + r*16][nn+3] = v.w;
        }
        __syncthreads();
        int n = tid >> 2, kq = tid & 3;
        s8v p0, p1;
        #pragma unroll
        for (int j = 0; j < 8; j++) p0[j] = (short)f2bf(lds[kq*16 + j][n]);
        #pragma unroll
        for (int j = 0; j < 8; j++) p1[j] = (short)f2bf(lds[kq*16 + 8 + j][n]);
        unsigned short* dst = Wt + ((size_t)(e*H1 + n0 + n))*D_IN + k0 + kq*16;
        *(s8v*)dst       = p0;
        *(s8v*)(dst + 8) = p1;
        return;
    }
    int pos = blockIdx.x;
    int row = perm[pos];
    unsigned short* xr = xs + (size_t)pos * D_IN;
    if (row < 0){
        s8v z = {0,0,0,0,0,0,0,0};
        for (int t = tid; t < D_IN/8; t += blockDim.x) *(s8v*)(xr + t*8) = z;
        return;
    }
    int d = desc_idx[row];
    int s = side_flag[row];
    __shared__ int pidx[64];
    if (tid < 64) pidx[tid] = piece_idx[row*64 + tid];
    __syncthreads();
    const float* Wp  = s ? Wp_b  : Wp_w;
    const float* Wc  = s ? Wc_b  : Wc_w;
    const float* Wep = s ? Wep_b : Wep_w;
    const float* Wf  = s ? Wf_b  : Wf_w;
    int ep  = ep_file[row];
    int epc = ep > 0 ? ep : 0;
    float a = fifty_a[row];
    for (int t = tid; t < D_IN/8; t += blockDim.x){
        int i0 = t*8;
        float v[8];
        if (i0 < 2048){
            int sq = i0 >> 5, c0 = i0 & 31;
            int pc = pidx[sq];
            float msk = pc >= 0 ? 1.0f : 0.0f;
            int pcc = pc > 0 ? pc : 0;
            const float* base = Wp + (((size_t)d*64 + sq)*12 + pcc)*32 + c0;
            float4 a0 = *(const float4*)base;
            float4 a1 = *(const float4*)(base + 4);
            v[0]=a0.x*msk; v[1]=a0.y*msk; v[2]=a0.z*msk; v[3]=a0.w*msk;
            v[4]=a1.x*msk; v[5]=a1.y*msk; v[6]=a1.z*msk; v[7]=a1.w*msk;
        } else if (i0 < 2176){
            int j = i0 - 2048; int ci = j >> 5, c0 = j & 31;
            float cv = castle_ms[row*4 + ci];
            const float* base = Wc + ((size_t)d*4 + ci)*32 + c0;
            float4 a0 = *(const float4*)base;
            float4 a1 = *(const float4*)(base + 4);
            v[0]=a0.x*cv; v[1]=a0.y*cv; v[2]=a0.z*cv; v[3]=a0.w*cv;
            v[4]=a1.x*cv; v[5]=a1.y*cv; v[6]=a1.z*cv; v[7]=a1.w*cv;
        } else if (i0 < 2208){
            int c0 = i0 - 2176;
            float msk = ep >= 0 ? 1.0f : 0.0f;
            const float* base = Wep + ((size_t)d*8 + epc)*32 + c0;
            float4 a0 = *(const float4*)base;
            float4 a1 = *(const float4*)(base + 4);
            v[0]=a0.x*msk; v[1]=a0.y*msk; v[2]=a0.z*msk; v[3]=a0.w*msk;
            v[4]=a1.x*msk; v[5]=a1.y*msk; v[6]=a1.z*msk; v[7]=a1.w*msk;
        } else {
            int c0 = i0 - 2208;
            #pragma unroll
            for (int j = 0; j < 8; j++)
                v[j] = (1.0f - a) * Wf[(size_t)d*64 + c0 + j] + a * Wf[(size_t)d*64 + 32 + c0 + j];
        }
        s8v p;
        #pragma unroll
        for (int j = 0; j < 8; j++) p[j] = (short)f2bf(v[j]);
        *(s8v*)(xr + i0) = p;
    }
}

// ------- fc1 MFMA: groups of 128 rows x 256 cols, K split 4, partial f32 out -------
__launch_bounds__(256)
__global__ void k_fc1(const int4* __restrict__ garr, const int* __restrict__ ngroups,
                      const unsigned short* __restrict__ xs,
                      const unsigned short* __restrict__ Wt,
                      float* __restrict__ h1p){
    int g = blockIdx.x;
    if (g >= *ngroups) return;
    int4 gi = garr[g];
    int tile0 = gi.x, e = gi.y, nv = gi.z;
    int kc = blockIdx.y, nh = blockIdx.z;
    int kstart = (kc <= 2) ? kc*18 : 53;
    int nsteps = (kc < 2) ? 18 : 17;
    int lane = threadIdx.x & 63, wave = threadIdx.x >> 6;
    int quad = lane >> 4, l16 = lane & 15;
    int col0 = nh*128 + wave*32 + l16;
    const unsigned short* Ab = xs + (size_t)(tile0*MT + l16)*D_IN + quad*8;
    const unsigned short* B0 = Wt + ((size_t)e*H1 + col0)*D_IN + quad*8;
    const unsigned short* B1 = B0 + (size_t)16*D_IN;
    f4v acc[8][2];
    #pragma unroll
    for (int mt = 0; mt < 8; mt++){ acc[mt][0] = (f4v){0.f,0.f,0.f,0.f}; acc[mt][1] = (f4v){0.f,0.f,0.f,0.f}; }
    int kend = kstart + nsteps;
    #pragma unroll 2
    for (int s = kstart; s < kend; s++){
        int ko = s*32;
        s8v b0 = *(const s8v*)(B0 + ko);
        s8v b1 = *(const s8v*)(B1 + ko);
        #pragma unroll
        for (int mt = 0; mt < 8; mt++){
            s8v av = *(const s8v*)(Ab + (size_t)mt*MT*D_IN + ko);
            acc[mt][0] = __builtin_amdgcn_mfma_f32_16x16x32_bf16(av, b0, acc[mt][0], 0, 0, 0);
            acc[mt][1] = __builtin_amdgcn_mfma_f32_16x16x32_bf16(av, b1, acc[mt][1], 0, 0, 0);
        }
    }
    float* out = h1p + (size_t)kc*NROWS*H1;
    #pragma unroll
    for (int mt = 0; mt < 8; mt++){
        if (mt >= nv) break;
        int posb = (tile0 + mt)*MT + quad*4;
        #pragma unroll
        for (int r = 0; r < 4; r++){
            out[(size_t)(posb + r)*H1 + col0]      = acc[mt][0][r];
            out[(size_t)(posb + r)*H1 + col0 + 16] = acc[mt][1][r];
        }
    }
}

// ------- fused tail: half-tile blocks (8 rows, 256 thr, 2 rows/wave like r2) -------
// 572 blocks x ~45KB LDS -> 3 blocks/CU resident -> no dispatch tail (286x512 had
// 226 CUs idle during the straggler half). Residual-block weights double-buffered
// in LDS (2x4KB), staged global->reg during compute, packed->LDS before barrier.
__launch_bounds__(256)
__global__ void k_tail(const int* __restrict__ tile_e, const int* __restrict__ perm,
                       const float* __restrict__ h1p, const float* __restrict__ b1,
                       const float* __restrict__ g1, const float* __restrict__ be1,
                       const float* __restrict__ W2, const float* __restrict__ b2,
                       const float* __restrict__ g2, const float* __restrict__ be2,
                       const float* __restrict__ Aw, const float* __restrict__ Abv,
                       const float* __restrict__ Ag, const float* __restrict__ Abe,
                       const float* __restrict__ Bw, const float* __restrict__ Bb,
                       const float* __restrict__ Bg, const float* __restrict__ Bbe,
                       const float* __restrict__ Ow, const float* __restrict__ Ob,
                       const float* __restrict__ bins,
                       float* __restrict__ out){
    int th = blockIdx.x;
    int t  = th >> 1;
    int r0 = (th & 1) * 8;          // half-tile row base
    int e = tile_e[t];
    if (e < 0) return;
    int tid = threadIdx.x;

    __shared__ __align__(16) float        shf[8*260];      // 8.3 KB
    __shared__ __align__(16) unsigned int W2pk[4096];      // 16 KB
    __shared__ __align__(16) float        vecs[NBLK*6*32]; // 9 KB
    __shared__ __align__(16) unsigned int wbuf[2][1024];   // 8 KB dbuf
    __shared__ __align__(16) float        sh2[8][36];
    __shared__ __align__(16) float        sh3[8][36];

    // ---- phase 1a: W2 -> bf16 k-pair packed ----
    {
        const float* W2e = W2 + (size_t)e*H1*H2;
        for (int j = tid; j < 4096; j += 256){
            int h = j & 1, q = j >> 1, cc = q & 31, p2 = q >> 5;
            int k0 = 4*p2 + 2*h;
            unsigned int lo = f2bf(W2e[k0*32 + cc]);
            unsigned int hi = f2bf(W2e[(k0+1)*32 + cc]);
            W2pk[(p2*32 + cc)*2 + h] = lo | (hi << 16);
        }
    }
    // ---- phase 1b: LN/bias vectors for all 12 blocks ----
    for (int j = tid; j < NBLK*6*32; j += 256){
        int cc = j & 31, vi = (j >> 5) % 6, tb = j / 192;
        size_t wb = (size_t)tb*E + e;
        const float* src;
        switch(vi){ case 0: src=Abv; break; case 1: src=Ag; break; case 2: src=Abe; break;
                    case 3: src=Bb;  break; case 4: src=Bg; break; default: src=Bbe; }
        vecs[j] = src[wb*32 + cc];
    }
    // ---- phase 1c: stage residual block 0 weights into wbuf[0] ----
    {
        size_t base = (size_t)e*1024;   // tb = 0
        #pragma unroll
        for (int k = 0; k < 4; k++){
            int s_all = k*256 + tid;
            int s = s_all & 511;
            int h = s & 1, q = s >> 1, cc = q & 31, p2 = q >> 5;
            int k0 = 4*p2 + 2*h;
            const float* src = (s_all >> 9) ? Bw : Aw;
            unsigned int lo = f2bf(src[base + k0*32 + cc]);
            unsigned int hi = f2bf(src[base + (k0+1)*32 + cc]);
            wbuf[0][s_all] = lo | (hi << 16);
        }
    }
    // ---- phase 1d: sum fc1 K-partials + bias + gelu -> shf ----
    #pragma unroll
    for (int it = 0; it < 2; it++){
        int slot = it*256 + tid;          // 8 rows x 64 col4s
        int r = slot >> 6, c4 = (slot & 63) << 2;
        int row = t*MT + r0 + r;
        float4 v = {0.f,0.f,0.f,0.f};
        #pragma unroll
        for (int kc = 0; kc < KSPLIT; kc++){
            float4 p = *(const float4*)(h1p + ((size_t)kc*NROWS + row)*H1 + c4);
            v.x += p.x; v.y += p.y; v.z += p.z; v.w += p.w;
        }
        float4 bb = *(const float4*)(b1 + e*H1 + c4);
        shf[r*260 + c4]   = gelu(v.x + bb.x);
        shf[r*260 + c4+1] = gelu(v.y + bb.y);
        shf[r*260 + c4+2] = gelu(v.z + bb.z);
        shf[r*260 + c4+3] = gelu(v.w + bb.w);
    }
    __syncthreads();

    int m = tid >> 5, c = tid & 31;     // 8 rows x 32 lanes, 2 rows per wave (r2 layout)
    // ---- LN1 (one-pass: parallel sum / sumsq reductions) ----
    {
        float s = 0.f, s2 = 0.f;
        #pragma unroll
        for (int j = 0; j < 8; j++){
            float x = shf[m*260 + c + 32*j];
            s += x; s2 += x*x;
        }
        s  = red32(s);
        s2 = red32(s2);
        float mean = s * (1.0f/H1);
        float var  = s2 * (1.0f/H1) - mean*mean;
        float rs = rsqrtf(var + 1e-5f);
        #pragma unroll
        for (int j = 0; j < 8; j++){
            int k = c + 32*j;
            shf[m*260 + k] = (shf[m*260 + k] - mean) * rs * g1[e*H1 + k] + be1[e*H1 + k];
        }
    }
    // ---- fc2 GEMV [256->32] + gelu + LN2 (one-pass) ----
    float hv;
    {
        const uint2* W2p = (const uint2*)W2pk;
        float q0=0.f,q1=0.f,q2=0.f,q3=0.f;
        #pragma unroll 8
        for (int p2 = 0; p2 < 64; p2++){
            uint2 w = W2p[p2*32 + c];
            float4 h4 = *(const float4*)(shf + m*260 + p2*4);
            q0 = fmaf(h4.x, bflo(w.x), q0);
            q1 = fmaf(h4.y, bfhi(w.x), q1);
            q2 = fmaf(h4.z, bflo(w.y), q2);
            q3 = fmaf(h4.w, bfhi(w.y), q3);
        }
        float acc = (q0+q1) + (q2+q3) + b2[e*H2 + c];
        float y = gelu(acc);
        float s  = red32(y);
        float s2 = red32(y*y);
        float mean2 = s * (1.0f/H2);
        float var2  = s2 * (1.0f/H2) - mean2*mean2;
        hv = (y - mean2) * rsqrtf(var2 + 1e-5f) * g2[e*H2+c] + be2[e*H2+c];
    }

    // ---- 12 residual blocks: dbuf weight staging, one-pass LN ----
    int cur = 0;
    for (int tb = 0; tb < NBLK; tb++){
        // issue next block's weight loads early (consumed after compute)
        float wfa[4], wfb[4];
        int tbn = tb + 1;
        if (tbn < NBLK){
            size_t base = ((size_t)tbn*E + e)*1024;
            #pragma unroll
            for (int k = 0; k < 4; k++){
                int s_all = k*256 + tid;
                int s = s_all & 511;
                int h = s & 1, q = s >> 1, cc = q & 31, p2 = q >> 5;
                int k0 = 4*p2 + 2*h;
                const float* src = (s_all >> 9) ? Bw : Aw;
                wfa[k] = src[base + k0*32 + cc];
                wfb[k] = src[base + (k0+1)*32 + cc];
            }
        }
        const float* vA = &vecs[tb*192];
        const uint2* WA = (const uint2*)&wbuf[cur][0];
        const uint2* WB = (const uint2*)&wbuf[cur][512];
        sh2[m][c] = hv;
        float q0=0.f,q1=0.f,q2=0.f,q3=0.f;
        #pragma unroll
        for (int p2 = 0; p2 < 8; p2++){
            uint2 w = WA[p2*32 + c];
            float4 h4 = *(const float4*)(&sh2[m][p2*4]);
            q0 = fmaf(h4.x, bflo(w.x), q0);
            q1 = fmaf(h4.y, bfhi(w.x), q1);
            q2 = fmaf(h4.z, bflo(w.y), q2);
            q3 = fmaf(h4.w, bfhi(w.y), q3);
        }
        float ya = (q0+q1) + (q2+q3) + vA[c];
        ya = gelu(ya);
        float sa  = red32(ya);
        float sa2 = red32(ya*ya);
        float ma = sa * (1.0f/H2);
        float va = sa2 * (1.0f/H2) - ma*ma;
        float yA = (ya - ma) * rsqrtf(va + 1e-5f) * vA[32+c] + vA[64+c];
        sh3[m][c] = yA;
        q0=0.f; q1=0.f; q2=0.f; q3=0.f;
        #pragma unroll
        for (int p2 = 0; p2 < 8; p2++){
            uint2 w = WB[p2*32 + c];
            float4 h4 = *(const float4*)(&sh3[m][p2*4]);
            q0 = fmaf(h4.x, bflo(w.x), q0);
            q1 = fmaf(h4.y, bfhi(w.x), q1);
            q2 = fmaf(h4.z, bflo(w.y), q2);
            q3 = fmaf(h4.w, bfhi(w.y), q3);
        }
        float yb = (q0+q1) + (q2+q3) + vA[96+c];
        yb = gelu(yb);
        float sb  = red32(yb);
        float sb2 = red32(yb*yb);
        float mb = sb * (1.0f/H2);
        float vb = sb2 * (1.0f/H2) - mb*mb;
        hv += (yb - mb) * rsqrtf(vb + 1e-5f) * vA[128+c] + vA[160+c];
        // pack + write next block's weights, then barrier for cross-wave visibility
        if (tbn < NBLK){
            #pragma unroll
            for (int k = 0; k < 4; k++){
                int s_all = k*256 + tid;
                unsigned int lo = f2bf(wfa[k]);
                unsigned int hi = f2bf(wfb[k]);
                wbuf[cur^1][s_all] = lo | (hi << 16);
            }
        }
        cur ^= 1;
        __syncthreads();
    }

    // ---- out-proj + softmax + p_win ----
    sh2[m][c] = gelu(hv);
    __syncthreads();
    int wave = tid >> 6, lane = tid & 63;
    const float* W = Ow + (size_t)e*32*NOUT;
    for (int rr = wave; rr < 8; rr += 4){
        int orow = perm[t*MT + r0 + rr];
        if (orow < 0) continue;
        float acc = (lane < NOUT) ? Ob[e*NOUT + lane] : -INFINITY;
        #pragma unroll
        for (int k = 0; k < 32; k++){
            float gk = sh2[rr][k];
            if (lane < NOUT) acc = fmaf(gk, W[k*NOUT + lane], acc);
        }
        if (lane < NOUT) out[(size_t)orow*NOUT + lane] = acc;
        float mx = acc;
        #pragma unroll
        for (int o = 32; o > 0; o >>= 1) mx = fmaxf(mx, __shfl_xor(mx, o));
        float pp = (lane < NOUT) ? expf(acc - mx) : 0.0f;
        float sum = pp;
        float pb = (lane < NOUT) ? pp * bins[lane] : 0.0f;
        float sb = pb;
        #pragma unroll
        for (int o = 32; o > 0; o >>= 1){ sum += __shfl_xor(sum, o); sb += __shfl_xor(sb, o); }
        if (lane == 0) out[(size_t)N*NOUT + orow] = sb / sum;
    }
}

extern "C" void kernel_launch(void* const* d_in, const int* in_sizes, int n_in,
                              void* d_out, int out_size, void* d_ws, size_t ws_size,
                              hipStream_t stream){
    const int*   piece_idx = (const int*)d_in[0];
    const int*   side_flag = (const int*)d_in[1];
    const int*   ep_file   = (const int*)d_in[2];
    const float* castle_ms = (const float*)d_in[3];
    const float* fifty_a   = (const float*)d_in[4];
    const int*   desc      = (const int*)d_in[5];
    const float* Wp_w  = (const float*)d_in[6];
    const float* Wp_b  = (const float*)d_in[7];
    const float* Wc_w  = (const float*)d_in[8];
    const float* Wc_b  = (const float*)d_in[9];
    const float* Wep_w = (const float*)d_in[10];
    const float* Wep_b = (const float*)d_in[11];
    const float* Wf_w  = (const float*)d_in[12];
    const float* Wf_b  = (const float*)d_in[13];
    const float* fc1_w = (const float*)d_in[14];
    const float* fc1_b = (const float*)d_in[15];
    const float* ln1_g = (const float*)d_in[16];
    const float* ln1_b = (const float*)d_in[17];
    const float* fc2_w = (const float*)d_in[18];
    const float* fc2_b = (const float*)d_in[19];
    const float* ln2_g = (const float*)d_in[20];
    const float* ln2_b = (const float*)d_in[21];
    const float* blkA_w  = (const float*)d_in[22];
    const float* blkA_b  = (const float*)d_in[23];
    const float* blkA_g  = (const float*)d_in[24];
    const float* blkA_be = (const float*)d_in[25];
    const float* blkB_w  = (const float*)d_in[26];
    const float* blkB_b  = (const float*)d_in[27];
    const float* blkB_g  = (const float*)d_in[28];
    const float* blkB_be = (const float*)d_in[29];
    const float* out_w = (const float*)d_in[30];
    const float* out_b = (const float*)d_in[31];
    const float* bins  = (const float*)d_in[32];

    char* wsp = (char*)d_ws;
    auto alloc = [&](size_t bytes){ void* p = (void*)wsp; wsp += (bytes + 255) & ~(size_t)255; return p; };
    int*            perm    = (int*)            alloc((size_t)NPAD*4);
    int*            tile_e  = (int*)            alloc((size_t)NTILE*4);
    int4*           garr    = (int4*)           alloc((size_t)GMAX*16);
    int*            ngroups = (int*)            alloc(256);
    unsigned short* Wt      = (unsigned short*) alloc((size_t)E*H1*D_IN*2);
    unsigned short* xs      = (unsigned short*) alloc((size_t)(NPAD+128)*D_IN*2);
    float*          h1p     = (float*)          alloc((size_t)KSPLIT*NROWS*H1*4);

    k_sort<<<1, 256, 0, stream>>>(desc, perm, tile_e, garr, ngroups);
    k_prep<<<NPAD + NCONVBLK, 256, 0, stream>>>(perm, piece_idx, side_flag, ep_file,
                                                castle_ms, fifty_a, desc,
                                                Wp_w, Wp_b, Wc_w, Wc_b,
                                                Wep_w, Wep_b, Wf_w, Wf_b,
                                                xs, fc1_w, Wt);
    k_fc1<<<dim3(GMAX, KSPLIT, 2), 256, 0, stream>>>(garr, ngroups, xs, Wt, h1p);
    k_tail<<<NTILE*2, 256, 0, stream>>>(tile_e, perm, h1p, fc1_b, ln1_g, ln1_b,
                                        fc2_w, fc2_b, ln2_g, ln2_b,
                                        blkA_w, blkA_b, blkA_g, blkA_be,
                                        blkB_w, blkB_b, blkB_g, blkB_be,
                                        out_w, out_b, bins, (float*)d_out);
}

// Round 7
// 282.584 us; speedup vs baseline: 1.1753x; 1.0636x over previous
//
#include <hip/hip_runtime.h>
#include <math.h>

#define N 4096
#define E 32
#define NBLK 12
#define D_IN 2240
#define H1 256
#define H2 32
#define NOUT 51
#define MT 16
#define NPAD (N + E*(MT-1))   // 4576
#define NTILE (NPAD/MT)       // 286
#define KSPLIT 4
#define NROWS 4608
#define GMAX 96

typedef short s8v __attribute__((ext_vector_type(8)));
typedef float f4v __attribute__((ext_vector_type(4)));

__device__ __forceinline__ float gelu(float x){
    return 0.5f * x * (1.0f + erff(x * 0.70710678118654752f));
}
__device__ __forceinline__ unsigned short f2bf(float f){
    unsigned int u = __float_as_uint(f);
    unsigned int r = (u + 0x7fffu + ((u >> 16) & 1u)) >> 16;
    return (unsigned short)r;
}
__device__ __forceinline__ float bflo(unsigned int u){ return __uint_as_float(u << 16); }
__device__ __forceinline__ float bfhi(unsigned int u){ return __uint_as_float(u & 0xffff0000u); }

// --- DPP rotation-butterfly reduction over each 32-lane half (sum) ---
template<int CTRL>
__device__ __forceinline__ float dppadd(float x){
    int y = __builtin_amdgcn_update_dpp(0, __float_as_int(x), CTRL, 0xF, 0xF, true);
    return x + __int_as_float(y);
}
__device__ __forceinline__ float red32(float x){
    x = dppadd<0x121>(x);   // row_ror:1
    x = dppadd<0x122>(x);   // row_ror:2
    x = dppadd<0x124>(x);   // row_ror:4
    x = dppadd<0x128>(x);   // row_ror:8  -> each 16-group holds its sum
    int y = __builtin_amdgcn_ds_swizzle(__float_as_int(x), 0x401F);  // xor16
    return x + __int_as_float(y);
}

// ---- merged: block 0 = sort (+zero row), blocks 1..N = feature build (unsorted xs) ----
__global__ void k_prep(const int* __restrict__ piece_idx,
                       const int* __restrict__ side_flag,
                       const int* __restrict__ ep_file,
                       const float* __restrict__ castle_ms,
                       const float* __restrict__ fifty_a,
                       const int* __restrict__ desc_idx,
                       const float* __restrict__ Wp_w, const float* __restrict__ Wp_b,
                       const float* __restrict__ Wc_w, const float* __restrict__ Wc_b,
                       const float* __restrict__ Wep_w, const float* __restrict__ Wep_b,
                       const float* __restrict__ Wf_w, const float* __restrict__ Wf_b,
                       unsigned short* __restrict__ xs,
                       int* __restrict__ perm, int* __restrict__ tile_e,
                       int4* __restrict__ garr, int* __restrict__ ngroups){
    int tid = threadIdx.x;
    if (blockIdx.x == 0){
        // ---------------- sort rows by expert + build 8-tile groups ----------------
        __shared__ int scnt[E];
        __shared__ int spoff[E+1];
        __shared__ int scur[E];
        if (tid < E) scnt[tid] = 0;
        __syncthreads();
        for (int n = tid; n < N; n += blockDim.x) atomicAdd(&scnt[desc_idx[n]], 1);
        __syncthreads();
        if (tid == 0){
            int run = 0;
            for (int e = 0; e < E; e++){ spoff[e] = run; run += ((scnt[e] + MT - 1)/MT)*MT; }
            spoff[E] = run;
            int ng = 0;
            for (int e = 0; e < E; e++){
                int t0 = spoff[e]/MT, t1 = spoff[e+1]/MT;
                for (int t = t0; t < t1; t += 8){
                    int nv = t1 - t; if (nv > 8) nv = 8;
                    if (ng < GMAX) garr[ng] = make_int4(t, e, nv, 0);
                    ng++;
                }
            }
            *ngroups = (ng > GMAX) ? GMAX : ng;
        }
        __syncthreads();
        if (tid < E) scur[tid] = spoff[tid];
        for (int p = tid; p < NPAD + 64; p += blockDim.x) perm[p] = -1;
        __syncthreads();
        for (int n = tid; n < N; n += blockDim.x){
            int p = atomicAdd(&scur[desc_idx[n]], 1);
            perm[p] = n;
        }
        for (int t = tid; t < NTILE; t += blockDim.x){
            int p0 = t*MT;
            int e = -1;
            if (p0 < spoff[E]){
                for (int q = 0; q < E; q++){
                    if (p0 >= spoff[q] && p0 < spoff[q+1]){ e = q; break; }
                }
            }
            tile_e[t] = e;
        }
        // zero row N of xs (pad rows in fc1 gather point here)
        s8v z = {0,0,0,0,0,0,0,0};
        for (int i = tid; i < D_IN/8; i += blockDim.x)
            *(s8v*)(xs + (size_t)N*D_IN + i*8) = z;
        return;
    }
    int row = blockIdx.x - 1;
    unsigned short* xr = xs + (size_t)row * D_IN;
    int d = desc_idx[row];
    int s = side_flag[row];
    __shared__ int pidx[64];
    if (tid < 64) pidx[tid] = piece_idx[row*64 + tid];
    __syncthreads();
    const float* Wp  = s ? Wp_b  : Wp_w;
    const float* Wc  = s ? Wc_b  : Wc_w;
    const float* Wep = s ? Wep_b : Wep_w;
    const float* Wf  = s ? Wf_b  : Wf_w;
    int ep  = ep_file[row];
    int epc = ep > 0 ? ep : 0;
    float a = fifty_a[row];
    for (int t = tid; t < D_IN/8; t += blockDim.x){
        int i0 = t*8;
        float v[8];
        if (i0 < 2048){
            int sq = i0 >> 5, c0 = i0 & 31;
            int pc = pidx[sq];
            float msk = pc >= 0 ? 1.0f : 0.0f;
            int pcc = pc > 0 ? pc : 0;
            const float* base = Wp + (((size_t)d*64 + sq)*12 + pcc)*32 + c0;
            float4 a0 = *(const float4*)base;
            float4 a1 = *(const float4*)(base + 4);
            v[0]=a0.x*msk; v[1]=a0.y*msk; v[2]=a0.z*msk; v[3]=a0.w*msk;
            v[4]=a1.x*msk; v[5]=a1.y*msk; v[6]=a1.z*msk; v[7]=a1.w*msk;
        } else if (i0 < 2176){
            int j = i0 - 2048; int ci = j >> 5, c0 = j & 31;
            float cv = castle_ms[row*4 + ci];
            const float* base = Wc + ((size_t)d*4 + ci)*32 + c0;
            float4 a0 = *(const float4*)base;
            float4 a1 = *(const float4*)(base + 4);
            v[0]=a0.x*cv; v[1]=a0.y*cv; v[2]=a0.z*cv; v[3]=a0.w*cv;
            v[4]=a1.x*cv; v[5]=a1.y*cv; v[6]=a1.z*cv; v[7]=a1.w*cv;
        } else if (i0 < 2208){
            int c0 = i0 - 2176;
            float msk = ep >= 0 ? 1.0f : 0.0f;
            const float* base = Wep + ((size_t)d*8 + epc)*32 + c0;
            float4 a0 = *(const float4*)base;
            float4 a1 = *(const float4*)(base + 4);
            v[0]=a0.x*msk; v[1]=a0.y*msk; v[2]=a0.z*msk; v[3]=a0.w*msk;
            v[4]=a1.x*msk; v[5]=a1.y*msk; v[6]=a1.z*msk; v[7]=a1.w*msk;
        } else {
            int c0 = i0 - 2208;
            #pragma unroll
            for (int j = 0; j < 8; j++)
                v[j] = (1.0f - a) * Wf[(size_t)d*64 + c0 + j] + a * Wf[(size_t)d*64 + 32 + c0 + j];
        }
        s8v p;
        #pragma unroll
        for (int j = 0; j < 8; j++) p[j] = (short)f2bf(v[j]);
        *(s8v*)(xr + i0) = p;
    }
}

// ------- fc1 MFMA: B staged from f32 fc1_w via LDS (Wt intermediate eliminated),
//         A gathered per-lane through perm from unsorted xs (pads -> zero row N) -------
__launch_bounds__(256)
__global__ void k_fc1(const int4* __restrict__ garr, const int* __restrict__ ngroups,
                      const unsigned short* __restrict__ xs,
                      const int* __restrict__ perm,
                      const float* __restrict__ W1,
                      float* __restrict__ h1p){
    int g = blockIdx.x;
    if (g >= *ngroups) return;
    int4 gi = garr[g];
    int tile0 = gi.x, e = gi.y, nv = gi.z;
    int kc = blockIdx.y, nh = blockIdx.z;
    int kstart = (kc <= 2) ? kc*18 : 53;
    int nsteps = (kc < 2) ? 18 : 17;
    int tid = threadIdx.x;
    int lane = tid & 63, wave = tid >> 6;
    int quad = lane >> 4, l16 = lane & 15;

    __shared__ float bst[32][133];   // 32 k x 128 n f32, pad 133 (bank spread + b32-aligned)

    // per-lane A row bases (perm gather; -1/-overhang -> zero row N)
    const unsigned short* Arow[8];
    #pragma unroll
    for (int mt = 0; mt < 8; mt++){
        int p = perm[(tile0 + mt)*MT + l16];
        if (p < 0) p = N;
        Arow[mt] = xs + (size_t)p*D_IN + quad*8;
    }

    const float* Wb = W1 + (size_t)e*D_IN*H1 + nh*128;
    int kk0 = tid >> 5;          // 0..7
    int nq4 = (tid & 31) << 2;   // 0..124
    int cl0 = wave*32 + l16;     // col within 128
    int cl1 = cl0 + 16;

    f4v acc[8][2];
    #pragma unroll
    for (int mt = 0; mt < 8; mt++){ acc[mt][0] = (f4v){0.f,0.f,0.f,0.f}; acc[mt][1] = (f4v){0.f,0.f,0.f,0.f}; }

    int kend = kstart + nsteps;
    for (int s = kstart; s < kend; s++){
        int kb = s*32;
        // stage 32k x 128n f32 tile (coalesced 512B rows)
        #pragma unroll
        for (int p = 0; p < 4; p++){
            int kk = p*8 + kk0;
            float4 v = *(const float4*)(Wb + (size_t)(kb + kk)*H1 + nq4);
            bst[kk][nq4]   = v.x;
            bst[kk][nq4+1] = v.y;
            bst[kk][nq4+2] = v.z;
            bst[kk][nq4+3] = v.w;
        }
        __syncthreads();
        // B fragments: 8 k-contig f32 per col, convert to bf16
        s8v b0, b1;
        #pragma unroll
        for (int j = 0; j < 8; j++){
            b0[j] = (short)f2bf(bst[quad*8 + j][cl0]);
            b1[j] = (short)f2bf(bst[quad*8 + j][cl1]);
        }
        #pragma unroll
        for (int mt = 0; mt < 8; mt++){
            s8v av = *(const s8v*)(Arow[mt] + kb);
            acc[mt][0] = __builtin_amdgcn_mfma_f32_16x16x32_bf16(av, b0, acc[mt][0], 0, 0, 0);
            acc[mt][1] = __builtin_amdgcn_mfma_f32_16x16x32_bf16(av, b1, acc[mt][1], 0, 0, 0);
        }
        __syncthreads();
    }
    int col0 = nh*128 + wave*32 + l16;
    float* out = h1p + (size_t)kc*NROWS*H1;
    #pragma unroll
    for (int mt = 0; mt < 8; mt++){
        if (mt >= nv) break;
        int posb = (tile0 + mt)*MT + quad*4;
        #pragma unroll
        for (int r = 0; r < 4; r++){
            out[(size_t)(posb + r)*H1 + col0]      = acc[mt][0][r];
            out[(size_t)(posb + r)*H1 + col0 + 16] = acc[mt][1][r];
        }
    }
}

// ------- fused tail: half-tile blocks (8 rows, 256 thr, 2 rows/wave) -------
__launch_bounds__(256)
__global__ void k_tail(const int* __restrict__ tile_e, const int* __restrict__ perm,
                       const float* __restrict__ h1p, const float* __restrict__ b1,
                       const float* __restrict__ g1, const float* __restrict__ be1,
                       const float* __restrict__ W2, const float* __restrict__ b2,
                       const float* __restrict__ g2, const float* __restrict__ be2,
                       const float* __restrict__ Aw, const float* __restrict__ Abv,
                       const float* __restrict__ Ag, const float* __restrict__ Abe,
                       const float* __restrict__ Bw, const float* __restrict__ Bb,
                       const float* __restrict__ Bg, const float* __restrict__ Bbe,
                       const float* __restrict__ Ow, const float* __restrict__ Ob,
                       const float* __restrict__ bins,
                       float* __restrict__ out){
    int th = blockIdx.x;
    int t  = th >> 1;
    int r0 = (th & 1) * 8;          // half-tile row base
    int e = tile_e[t];
    if (e < 0) return;
    int tid = threadIdx.x;

    __shared__ __align__(16) float        shf[8*260];      // 8.3 KB
    __shared__ __align__(16) unsigned int W2pk[4096];      // 16 KB
    __shared__ __align__(16) float        vecs[NBLK*6*32]; // 9 KB
    __shared__ __align__(16) unsigned int wbuf[2][1024];   // 8 KB dbuf
    __shared__ __align__(16) float        sh2[8][36];
    __shared__ __align__(16) float        sh3[8][36];

    // ---- phase 1a: W2 -> bf16 k-pair packed ----
    {
        const float* W2e = W2 + (size_t)e*H1*H2;
        for (int j = tid; j < 4096; j += 256){
            int h = j & 1, q = j >> 1, cc = q & 31, p2 = q >> 5;
            int k0 = 4*p2 + 2*h;
            unsigned int lo = f2bf(W2e[k0*32 + cc]);
            unsigned int hi = f2bf(W2e[(k0+1)*32 + cc]);
            W2pk[(p2*32 + cc)*2 + h] = lo | (hi << 16);
        }
    }
    // ---- phase 1b: LN/bias vectors for all 12 blocks ----
    for (int j = tid; j < NBLK*6*32; j += 256){
        int cc = j & 31, vi = (j >> 5) % 6, tb = j / 192;
        size_t wb = (size_t)tb*E + e;
        const float* src;
        switch(vi){ case 0: src=Abv; break; case 1: src=Ag; break; case 2: src=Abe; break;
                    case 3: src=Bb;  break; case 4: src=Bg; break; default: src=Bbe; }
        vecs[j] = src[wb*32 + cc];
    }
    // ---- phase 1c: stage residual block 0 weights into wbuf[0] ----
    {
        size_t base = (size_t)e*1024;   // tb = 0
        #pragma unroll
        for (int k = 0; k < 4; k++){
            int s_all = k*256 + tid;
            int s = s_all & 511;
            int h = s & 1, q = s >> 1, cc = q & 31, p2 = q >> 5;
            int k0 = 4*p2 + 2*h;
            const float* src = (s_all >> 9) ? Bw : Aw;
            unsigned int lo = f2bf(src[base + k0*32 + cc]);
            unsigned int hi = f2bf(src[base + (k0+1)*32 + cc]);
            wbuf[0][s_all] = lo | (hi << 16);
        }
    }
    // ---- phase 1d: sum fc1 K-partials + bias + gelu -> shf ----
    #pragma unroll
    for (int it = 0; it < 2; it++){
        int slot = it*256 + tid;          // 8 rows x 64 col4s
        int r = slot >> 6, c4 = (slot & 63) << 2;
        int row = t*MT + r0 + r;
        float4 v = {0.f,0.f,0.f,0.f};
        #pragma unroll
        for (int kc = 0; kc < KSPLIT; kc++){
            float4 p = *(const float4*)(h1p + ((size_t)kc*NROWS + row)*H1 + c4);
            v.x += p.x; v.y += p.y; v.z += p.z; v.w += p.w;
        }
        float4 bb = *(const float4*)(b1 + e*H1 + c4);
        shf[r*260 + c4]   = gelu(v.x + bb.x);
        shf[r*260 + c4+1] = gelu(v.y + bb.y);
        shf[r*260 + c4+2] = gelu(v.z + bb.z);
        shf[r*260 + c4+3] = gelu(v.w + bb.w);
    }
    __syncthreads();

    int m = tid >> 5, c = tid & 31;     // 8 rows x 32 lanes, 2 rows per wave
    // ---- LN1 (one-pass: parallel sum / sumsq reductions) ----
    {
        float s = 0.f, s2 = 0.f;
        #pragma unroll
        for (int j = 0; j < 8; j++){
            float x = shf[m*260 + c + 32*j];
            s += x; s2 += x*x;
        }
        s  = red32(s);
        s2 = red32(s2);
        float mean = s * (1.0f/H1);
        float var  = s2 * (1.0f/H1) - mean*mean;
        float rs = rsqrtf(var + 1e-5f);
        #pragma unroll
        for (int j = 0; j < 8; j++){
            int k = c + 32*j;
            shf[m*260 + k] = (shf[m*260 + k] - mean) * rs * g1[e*H1 + k] + be1[e*H1 + k];
        }
    }
    // ---- fc2 GEMV [256->32] + gelu + LN2 (one-pass) ----
    float hv;
    {
        const uint2* W2p = (const uint2*)W2pk;
        float q0=0.f,q1=0.f,q2=0.f,q3=0.f;
        #pragma unroll 8
        for (int p2 = 0; p2 < 64; p2++){
            uint2 w = W2p[p2*32 + c];
            float4 h4 = *(const float4*)(shf + m*260 + p2*4);
            q0 = fmaf(h4.x, bflo(w.x), q0);
            q1 = fmaf(h4.y, bfhi(w.x), q1);
            q2 = fmaf(h4.z, bflo(w.y), q2);
            q3 = fmaf(h4.w, bfhi(w.y), q3);
        }
        float acc = (q0+q1) + (q2+q3) + b2[e*H2 + c];
        float y = gelu(acc);
        float s  = red32(y);
        float s2 = red32(y*y);
        float mean2 = s * (1.0f/H2);
        float var2  = s2 * (1.0f/H2) - mean2*mean2;
        hv = (y - mean2) * rsqrtf(var2 + 1e-5f) * g2[e*H2+c] + be2[e*H2+c];
    }

    // ---- 12 residual blocks: dbuf weight staging, one-pass LN ----
    int cur = 0;
    for (int tb = 0; tb < NBLK; tb++){
        float wfa[4], wfb[4];
        int tbn = tb + 1;
        if (tbn < NBLK){
            size_t base = ((size_t)tbn*E + e)*1024;
            #pragma unroll
            for (int k = 0; k < 4; k++){
                int s_all = k*256 + tid;
                int s = s_all & 511;
                int h = s & 1, q = s >> 1, cc = q & 31, p2 = q >> 5;
                int k0 = 4*p2 + 2*h;
                const float* src = (s_all >> 9) ? Bw : Aw;
                wfa[k] = src[base + k0*32 + cc];
                wfb[k] = src[base + (k0+1)*32 + cc];
            }
        }
        const float* vA = &vecs[tb*192];
        const uint2* WA = (const uint2*)&wbuf[cur][0];
        const uint2* WB = (const uint2*)&wbuf[cur][512];
        sh2[m][c] = hv;
        float q0=0.f,q1=0.f,q2=0.f,q3=0.f;
        #pragma unroll
        for (int p2 = 0; p2 < 8; p2++){
            uint2 w = WA[p2*32 + c];
            float4 h4 = *(const float4*)(&sh2[m][p2*4]);
            q0 = fmaf(h4.x, bflo(w.x), q0);
            q1 = fmaf(h4.y, bfhi(w.x), q1);
            q2 = fmaf(h4.z, bflo(w.y), q2);
            q3 = fmaf(h4.w, bfhi(w.y), q3);
        }
        float ya = (q0+q1) + (q2+q3) + vA[c];
        ya = gelu(ya);
        float sa  = red32(ya);
        float sa2 = red32(ya*ya);
        float ma = sa * (1.0f/H2);
        float va = sa2 * (1.0f/H2) - ma*ma;
        float yA = (ya - ma) * rsqrtf(va + 1e-5f) * vA[32+c] + vA[64+c];
        sh3[m][c] = yA;
        q0=0.f; q1=0.f; q2=0.f; q3=0.f;
        #pragma unroll
        for (int p2 = 0; p2 < 8; p2++){
            uint2 w = WB[p2*32 + c];
            float4 h4 = *(const float4*)(&sh3[m][p2*4]);
            q0 = fmaf(h4.x, bflo(w.x), q0);
            q1 = fmaf(h4.y, bfhi(w.x), q1);
            q2 = fmaf(h4.z, bflo(w.y), q2);
            q3 = fmaf(h4.w, bfhi(w.y), q3);
        }
        float yb = (q0+q1) + (q2+q3) + vA[96+c];
        yb = gelu(yb);
        float sb  = red32(yb);
        float sb2 = red32(yb*yb);
        float mb = sb * (1.0f/H2);
        float vb = sb2 * (1.0f/H2) - mb*mb;
        hv += (yb - mb) * rsqrtf(vb + 1e-5f) * vA[128+c] + vA[160+c];
        if (tbn < NBLK){
            #pragma unroll
            for (int k = 0; k < 4; k++){
                int s_all = k*256 + tid;
                unsigned int lo = f2bf(wfa[k]);
                unsigned int hi = f2bf(wfb[k]);
                wbuf[cur^1][s_all] = lo | (hi << 16);
            }
        }
        cur ^= 1;
        __syncthreads();
    }

    // ---- out-proj + softmax + p_win ----
    sh2[m][c] = gelu(hv);
    __syncthreads();
    int wave = tid >> 6, lane = tid & 63;
    const float* W = Ow + (size_t)e*32*NOUT;
    for (int rr = wave; rr < 8; rr += 4){
        int orow = perm[t*MT + r0 + rr];
        if (orow < 0) continue;
        float acc = (lane < NOUT) ? Ob[e*NOUT + lane] : -INFINITY;
        #pragma unroll
        for (int k = 0; k < 32; k++){
            float gk = sh2[rr][k];
            if (lane < NOUT) acc = fmaf(gk, W[k*NOUT + lane], acc);
        }
        if (lane < NOUT) out[(size_t)orow*NOUT + lane] = acc;
        float mx = acc;
        #pragma unroll
        for (int o = 32; o > 0; o >>= 1) mx = fmaxf(mx, __shfl_xor(mx, o));
        float pp = (lane < NOUT) ? expf(acc - mx) : 0.0f;
        float sum = pp;
        float pb = (lane < NOUT) ? pp * bins[lane] : 0.0f;
        float sb = pb;
        #pragma unroll
        for (int o = 32; o > 0; o >>= 1){ sum += __shfl_xor(sum, o); sb += __shfl_xor(sb, o); }
        if (lane == 0) out[(size_t)N*NOUT + orow] = sb / sum;
    }
}

extern "C" void kernel_launch(void* const* d_in, const int* in_sizes, int n_in,
                              void* d_out, int out_size, void* d_ws, size_t ws_size,
                              hipStream_t stream){
    const int*   piece_idx = (const int*)d_in[0];
    const int*   side_flag = (const int*)d_in[1];
    const int*   ep_file   = (const int*)d_in[2];
    const float* castle_ms = (const float*)d_in[3];
    const float* fifty_a   = (const float*)d_in[4];
    const int*   desc      = (const int*)d_in[5];
    const float* Wp_w  = (const float*)d_in[6];
    const float* Wp_b  = (const float*)d_in[7];
    const float* Wc_w  = (const float*)d_in[8];
    const float* Wc_b  = (const float*)d_in[9];
    const float* Wep_w = (const float*)d_in[10];
    const float* Wep_b = (const float*)d_in[11];
    const float* Wf_w  = (const float*)d_in[12];
    const float* Wf_b  = (const float*)d_in[13];
    const float* fc1_w = (const float*)d_in[14];
    const float* fc1_b = (const float*)d_in[15];
    const float* ln1_g = (const float*)d_in[16];
    const float* ln1_b = (const float*)d_in[17];
    const float* fc2_w = (const float*)d_in[18];
    const float* fc2_b = (const float*)d_in[19];
    const float* ln2_g = (const float*)d_in[20];
    const float* ln2_b = (const float*)d_in[21];
    const float* blkA_w  = (const float*)d_in[22];
    const float* blkA_b  = (const float*)d_in[23];
    const float* blkA_g  = (const float*)d_in[24];
    const float* blkA_be = (const float*)d_in[25];
    const float* blkB_w  = (const float*)d_in[26];
    const float* blkB_b  = (const float*)d_in[27];
    const float* blkB_g  = (const float*)d_in[28];
    const float* blkB_be = (const float*)d_in[29];
    const float* out_w = (const float*)d_in[30];
    const float* out_b = (const float*)d_in[31];
    const float* bins  = (const float*)d_in[32];

    char* wsp = (char*)d_ws;
    auto alloc = [&](size_t bytes){ void* p = (void*)wsp; wsp += (bytes + 255) & ~(size_t)255; return p; };
    int*            perm    = (int*)            alloc((size_t)(NPAD+128)*4);
    int*            tile_e  = (int*)            alloc((size_t)NTILE*4);
    int4*           garr    = (int4*)           alloc((size_t)GMAX*16);
    int*            ngroups = (int*)            alloc(256);
    unsigned short* xs      = (unsigned short*) alloc((size_t)(N+128)*D_IN*2);
    float*          h1p     = (float*)          alloc((size_t)KSPLIT*NROWS*H1*4);

    k_prep<<<1 + N, 256, 0, stream>>>(piece_idx, side_flag, ep_file,
                                      castle_ms, fifty_a, desc,
                                      Wp_w, Wp_b, Wc_w, Wc_b,
                                      Wep_w, Wep_b, Wf_w, Wf_b,
                                      xs, perm, tile_e, garr, ngroups);
    k_fc1<<<dim3(GMAX, KSPLIT, 2), 256, 0, stream>>>(garr, ngroups, xs, perm, fc1_w, h1p);
    k_tail<<<NTILE*2, 256, 0, stream>>>(tile_e, perm, h1p, fc1_b, ln1_g, ln1_b,
                                        fc2_w, fc2_b, ln2_g, ln2_b,
                                        blkA_w, blkA_b, blkA_g, blkA_be,
                                        blkB_w, blkB_b, blkB_g, blkB_be,
                                        out_w, out_b, bins, (float*)d_out);
}

// Round 8
// 280.855 us; speedup vs baseline: 1.1825x; 1.0062x over previous
//
#include <hip/hip_runtime.h>
#include <math.h>

#define N 4096
#define E 32
#define NBLK 12
#define D_IN 2240
#define H1 256
#define H2 32
#define NOUT 51
#define MT 16
#define NPAD (N + E*(MT-1))   // 4576
#define NTILE (NPAD/MT)       // 286
#define KSPLIT 4
#define NROWS 4608
#define GMAX 96

typedef short s8v __attribute__((ext_vector_type(8)));
typedef float f4v __attribute__((ext_vector_type(4)));

__device__ __forceinline__ float gelu(float x){
    return 0.5f * x * (1.0f + erff(x * 0.70710678118654752f));
}
__device__ __forceinline__ unsigned short f2bf(float f){
    unsigned int u = __float_as_uint(f);
    unsigned int r = (u + 0x7fffu + ((u >> 16) & 1u)) >> 16;
    return (unsigned short)r;
}
__device__ __forceinline__ float bflo(unsigned int u){ return __uint_as_float(u << 16); }
__device__ __forceinline__ float bfhi(unsigned int u){ return __uint_as_float(u & 0xffff0000u); }

// --- DPP rotation-butterfly reduction over each 32-lane half (sum) ---
template<int CTRL>
__device__ __forceinline__ float dppadd(float x){
    int y = __builtin_amdgcn_update_dpp(0, __float_as_int(x), CTRL, 0xF, 0xF, true);
    return x + __int_as_float(y);
}
__device__ __forceinline__ float red32(float x){
    x = dppadd<0x121>(x);   // row_ror:1
    x = dppadd<0x122>(x);   // row_ror:2
    x = dppadd<0x124>(x);   // row_ror:4
    x = dppadd<0x128>(x);   // row_ror:8  -> each 16-group holds its sum
    int y = __builtin_amdgcn_ds_swizzle(__float_as_int(x), 0x401F);  // xor16
    return x + __int_as_float(y);
}

// ---- pre-pack W2 + residual weights to bf16-pair u32 (removes per-block f2bf in k_tail) ----
__global__ void k_pack(const float* __restrict__ W2,
                       const float* __restrict__ Aw, const float* __restrict__ Bw,
                       unsigned int* __restrict__ w2pk_g, unsigned int* __restrict__ rpk_g){
    int j = blockIdx.x*256 + threadIdx.x;
    if (j < E*4096){
        int e = j >> 12, idx = j & 4095;
        int h = idx & 1, q = idx >> 1, cc = q & 31, p2 = q >> 5;
        int k0 = 4*p2 + 2*h;
        const float* W2e = W2 + (size_t)e*H1*H2;
        unsigned int lo = f2bf(W2e[k0*32 + cc]);
        unsigned int hi = f2bf(W2e[(k0+1)*32 + cc]);
        w2pk_g[((size_t)e << 12) + (p2*32 + cc)*2 + h] = lo | (hi << 16);
    } else {
        int i = j - E*4096;          // 0 .. 24*E*512-1
        int slot = i & 511;
        int m = i >> 9;              // m = mat*E + e, mat = tb*2 + s
        int e = m & 31, mat = m >> 5;
        int tb = mat >> 1, s = mat & 1;
        int h = slot & 1, q = slot >> 1, cc = q & 31, p2 = q >> 5;
        int k0 = 4*p2 + 2*h;
        const float* src = s ? Bw : Aw;
        size_t base = ((size_t)tb*E + e)*1024;
        unsigned int lo = f2bf(src[base + k0*32 + cc]);
        unsigned int hi = f2bf(src[base + (k0+1)*32 + cc]);
        rpk_g[((size_t)m << 9) + slot] = lo | (hi << 16);
    }
}

// ---- merged: block 0 = sort (+zero row), blocks 1..N = feature build (unsorted xs) ----
__global__ void k_prep(const int* __restrict__ piece_idx,
                       const int* __restrict__ side_flag,
                       const int* __restrict__ ep_file,
                       const float* __restrict__ castle_ms,
                       const float* __restrict__ fifty_a,
                       const int* __restrict__ desc_idx,
                       const float* __restrict__ Wp_w, const float* __restrict__ Wp_b,
                       const float* __restrict__ Wc_w, const float* __restrict__ Wc_b,
                       const float* __restrict__ Wep_w, const float* __restrict__ Wep_b,
                       const float* __restrict__ Wf_w, const float* __restrict__ Wf_b,
                       unsigned short* __restrict__ xs,
                       int* __restrict__ perm, int* __restrict__ tile_e,
                       int4* __restrict__ garr, int* __restrict__ ngroups){
    int tid = threadIdx.x;
    if (blockIdx.x == 0){
        __shared__ int scnt[E];
        __shared__ int spoff[E+1];
        __shared__ int scur[E];
        if (tid < E) scnt[tid] = 0;
        __syncthreads();
        for (int n = tid; n < N; n += blockDim.x) atomicAdd(&scnt[desc_idx[n]], 1);
        __syncthreads();
        if (tid == 0){
            int run = 0;
            for (int e = 0; e < E; e++){ spoff[e] = run; run += ((scnt[e] + MT - 1)/MT)*MT; }
            spoff[E] = run;
            int ng = 0;
            for (int e = 0; e < E; e++){
                int t0 = spoff[e]/MT, t1 = spoff[e+1]/MT;
                for (int t = t0; t < t1; t += 8){
                    int nv = t1 - t; if (nv > 8) nv = 8;
                    if (ng < GMAX) garr[ng] = make_int4(t, e, nv, 0);
                    ng++;
                }
            }
            *ngroups = (ng > GMAX) ? GMAX : ng;
        }
        __syncthreads();
        if (tid < E) scur[tid] = spoff[tid];
        for (int p = tid; p < NPAD + 64; p += blockDim.x) perm[p] = -1;
        __syncthreads();
        for (int n = tid; n < N; n += blockDim.x){
            int p = atomicAdd(&scur[desc_idx[n]], 1);
            perm[p] = n;
        }
        for (int t = tid; t < NTILE; t += blockDim.x){
            int p0 = t*MT;
            int e = -1;
            if (p0 < spoff[E]){
                for (int q = 0; q < E; q++){
                    if (p0 >= spoff[q] && p0 < spoff[q+1]){ e = q; break; }
                }
            }
            tile_e[t] = e;
        }
        s8v z = {0,0,0,0,0,0,0,0};
        for (int i = tid; i < D_IN/8; i += blockDim.x)
            *(s8v*)(xs + (size_t)N*D_IN + i*8) = z;
        return;
    }
    int row = blockIdx.x - 1;
    unsigned short* xr = xs + (size_t)row * D_IN;
    int d = desc_idx[row];
    int s = side_flag[row];
    __shared__ int pidx[64];
    if (tid < 64) pidx[tid] = piece_idx[row*64 + tid];
    __syncthreads();
    const float* Wp  = s ? Wp_b  : Wp_w;
    const float* Wc  = s ? Wc_b  : Wc_w;
    const float* Wep = s ? Wep_b : Wep_w;
    const float* Wf  = s ? Wf_b  : Wf_w;
    int ep  = ep_file[row];
    int epc = ep > 0 ? ep : 0;
    float a = fifty_a[row];
    for (int t = tid; t < D_IN/8; t += blockDim.x){
        int i0 = t*8;
        float v[8];
        if (i0 < 2048){
            int sq = i0 >> 5, c0 = i0 & 31;
            int pc = pidx[sq];
            float msk = pc >= 0 ? 1.0f : 0.0f;
            int pcc = pc > 0 ? pc : 0;
            const float* base = Wp + (((size_t)d*64 + sq)*12 + pcc)*32 + c0;
            float4 a0 = *(const float4*)base;
            float4 a1 = *(const float4*)(base + 4);
            v[0]=a0.x*msk; v[1]=a0.y*msk; v[2]=a0.z*msk; v[3]=a0.w*msk;
            v[4]=a1.x*msk; v[5]=a1.y*msk; v[6]=a1.z*msk; v[7]=a1.w*msk;
        } else if (i0 < 2176){
            int j = i0 - 2048; int ci = j >> 5, c0 = j & 31;
            float cv = castle_ms[row*4 + ci];
            const float* base = Wc + ((size_t)d*4 + ci)*32 + c0;
            float4 a0 = *(const float4*)base;
            float4 a1 = *(const float4*)(base + 4);
            v[0]=a0.x*cv; v[1]=a0.y*cv; v[2]=a0.z*cv; v[3]=a0.w*cv;
            v[4]=a1.x*cv; v[5]=a1.y*cv; v[6]=a1.z*cv; v[7]=a1.w*cv;
        } else if (i0 < 2208){
            int c0 = i0 - 2176;
            float msk = ep >= 0 ? 1.0f : 0.0f;
            const float* base = Wep + ((size_t)d*8 + epc)*32 + c0;
            float4 a0 = *(const float4*)base;
            float4 a1 = *(const float4*)(base + 4);
            v[0]=a0.x*msk; v[1]=a0.y*msk; v[2]=a0.z*msk; v[3]=a0.w*msk;
            v[4]=a1.x*msk; v[5]=a1.y*msk; v[6]=a1.z*msk; v[7]=a1.w*msk;
        } else {
            int c0 = i0 - 2208;
            #pragma unroll
            for (int j = 0; j < 8; j++)
                v[j] = (1.0f - a) * Wf[(size_t)d*64 + c0 + j] + a * Wf[(size_t)d*64 + 32 + c0 + j];
        }
        s8v p;
        #pragma unroll
        for (int j = 0; j < 8; j++) p[j] = (short)f2bf(v[j]);
        *(s8v*)(xr + i0) = p;
    }
}

// ------- fc1 MFMA: B staged from f32 fc1_w via LDS, A gathered via perm -------
__launch_bounds__(256)
__global__ void k_fc1(const int4* __restrict__ garr, const int* __restrict__ ngroups,
                      const unsigned short* __restrict__ xs,
                      const int* __restrict__ perm,
                      const float* __restrict__ W1,
                      float* __restrict__ h1p){
    int g = blockIdx.x;
    if (g >= *ngroups) return;
    int4 gi = garr[g];
    int tile0 = gi.x, e = gi.y, nv = gi.z;
    int kc = blockIdx.y, nh = blockIdx.z;
    int kstart = (kc <= 2) ? kc*18 : 53;
    int nsteps = (kc < 2) ? 18 : 17;
    int tid = threadIdx.x;
    int lane = tid & 63, wave = tid >> 6;
    int quad = lane >> 4, l16 = lane & 15;

    __shared__ float bst[32][133];

    const unsigned short* Arow[8];
    #pragma unroll
    for (int mt = 0; mt < 8; mt++){
        int p = perm[(tile0 + mt)*MT + l16];
        if (p < 0) p = N;
        Arow[mt] = xs + (size_t)p*D_IN + quad*8;
    }

    const float* Wb = W1 + (size_t)e*D_IN*H1 + nh*128;
    int kk0 = tid >> 5;
    int nq4 = (tid & 31) << 2;
    int cl0 = wave*32 + l16;
    int cl1 = cl0 + 16;

    f4v acc[8][2];
    #pragma unroll
    for (int mt = 0; mt < 8; mt++){ acc[mt][0] = (f4v){0.f,0.f,0.f,0.f}; acc[mt][1] = (f4v){0.f,0.f,0.f,0.f}; }

    int kend = kstart + nsteps;
    for (int s = kstart; s < kend; s++){
        int kb = s*32;
        #pragma unroll
        for (int p = 0; p < 4; p++){
            int kk = p*8 + kk0;
            float4 v = *(const float4*)(Wb + (size_t)(kb + kk)*H1 + nq4);
            bst[kk][nq4]   = v.x;
            bst[kk][nq4+1] = v.y;
            bst[kk][nq4+2] = v.z;
            bst[kk][nq4+3] = v.w;
        }
        __syncthreads();
        s8v b0, b1;
        #pragma unroll
        for (int j = 0; j < 8; j++){
            b0[j] = (short)f2bf(bst[quad*8 + j][cl0]);
            b1[j] = (short)f2bf(bst[quad*8 + j][cl1]);
        }
        #pragma unroll
        for (int mt = 0; mt < 8; mt++){
            s8v av = *(const s8v*)(Arow[mt] + kb);
            acc[mt][0] = __builtin_amdgcn_mfma_f32_16x16x32_bf16(av, b0, acc[mt][0], 0, 0, 0);
            acc[mt][1] = __builtin_amdgcn_mfma_f32_16x16x32_bf16(av, b1, acc[mt][1], 0, 0, 0);
        }
        __syncthreads();
    }
    int col0 = nh*128 + wave*32 + l16;
    float* out = h1p + (size_t)kc*NROWS*H1;
    #pragma unroll
    for (int mt = 0; mt < 8; mt++){
        if (mt >= nv) break;
        int posb = (tile0 + mt)*MT + quad*4;
        #pragma unroll
        for (int r = 0; r < 4; r++){
            out[(size_t)(posb + r)*H1 + col0]      = acc[mt][0][r];
            out[(size_t)(posb + r)*H1 + col0 + 16] = acc[mt][1][r];
        }
    }
}

// ------- fused tail: half-tile blocks, ZERO barriers in residual loop -------
// Residual weights read directly from packed global (rpk, L2-resident) -> wbuf
// dbuf + its 12 barriers deleted. W2pk staged by plain u32 copy (pre-packed).
__launch_bounds__(256)
__global__ void k_tail(const int* __restrict__ tile_e, const int* __restrict__ perm,
                       const float* __restrict__ h1p, const float* __restrict__ b1,
                       const float* __restrict__ g1, const float* __restrict__ be1,
                       const unsigned int* __restrict__ w2pk_g, const float* __restrict__ b2,
                       const float* __restrict__ g2, const float* __restrict__ be2,
                       const unsigned int* __restrict__ rpk,
                       const float* __restrict__ Abv, const float* __restrict__ Ag,
                       const float* __restrict__ Abe,
                       const float* __restrict__ Bb, const float* __restrict__ Bg,
                       const float* __restrict__ Bbe,
                       const float* __restrict__ Ow, const float* __restrict__ Ob,
                       const float* __restrict__ bins,
                       float* __restrict__ out){
    int th = blockIdx.x;
    int t  = th >> 1;
    int r0 = (th & 1) * 8;
    int e = tile_e[t];
    if (e < 0) return;
    int tid = threadIdx.x;

    __shared__ __align__(16) float        shf[8*260];      // 8.3 KB
    __shared__ __align__(16) unsigned int W2pk[4096];      // 16 KB
    __shared__ __align__(16) float        vecs[NBLK*6*32]; // 9 KB
    __shared__ __align__(16) float        sh2[8][36];
    __shared__ __align__(16) float        sh3[8][36];

    // ---- phase 1a: copy pre-packed W2 into LDS ----
    {
        const unsigned int* src = w2pk_g + ((size_t)e << 12);
        for (int j = tid; j < 4096; j += 256) W2pk[j] = src[j];
    }
    // ---- phase 1b: LN/bias vectors for all 12 blocks ----
    for (int j = tid; j < NBLK*6*32; j += 256){
        int cc = j & 31, vi = (j >> 5) % 6, tb = j / 192;
        size_t wb = (size_t)tb*E + e;
        const float* src;
        switch(vi){ case 0: src=Abv; break; case 1: src=Ag; break; case 2: src=Abe; break;
                    case 3: src=Bb;  break; case 4: src=Bg; break; default: src=Bbe; }
        vecs[j] = src[wb*32 + cc];
    }
    // ---- phase 1d: sum fc1 K-partials + bias + gelu -> shf ----
    #pragma unroll
    for (int it = 0; it < 2; it++){
        int slot = it*256 + tid;
        int r = slot >> 6, c4 = (slot & 63) << 2;
        int row = t*MT + r0 + r;
        float4 v = {0.f,0.f,0.f,0.f};
        #pragma unroll
        for (int kc = 0; kc < KSPLIT; kc++){
            float4 p = *(const float4*)(h1p + ((size_t)kc*NROWS + row)*H1 + c4);
            v.x += p.x; v.y += p.y; v.z += p.z; v.w += p.w;
        }
        float4 bb = *(const float4*)(b1 + e*H1 + c4);
        shf[r*260 + c4]   = gelu(v.x + bb.x);
        shf[r*260 + c4+1] = gelu(v.y + bb.y);
        shf[r*260 + c4+2] = gelu(v.z + bb.z);
        shf[r*260 + c4+3] = gelu(v.w + bb.w);
    }
    __syncthreads();

    int m = tid >> 5, c = tid & 31;
    // ---- LN1 (one-pass) ----
    {
        float s = 0.f, s2 = 0.f;
        #pragma unroll
        for (int j = 0; j < 8; j++){
            float x = shf[m*260 + c + 32*j];
            s += x; s2 += x*x;
        }
        s  = red32(s);
        s2 = red32(s2);
        float mean = s * (1.0f/H1);
        float var  = s2 * (1.0f/H1) - mean*mean;
        float rs = rsqrtf(var + 1e-5f);
        #pragma unroll
        for (int j = 0; j < 8; j++){
            int k = c + 32*j;
            shf[m*260 + k] = (shf[m*260 + k] - mean) * rs * g1[e*H1 + k] + be1[e*H1 + k];
        }
    }
    // ---- fc2 GEMV [256->32] + gelu + LN2 ----
    float hv;
    {
        const uint2* W2p = (const uint2*)W2pk;
        float q0=0.f,q1=0.f,q2=0.f,q3=0.f;
        #pragma unroll 8
        for (int p2 = 0; p2 < 64; p2++){
            uint2 w = W2p[p2*32 + c];
            float4 h4 = *(const float4*)(shf + m*260 + p2*4);
            q0 = fmaf(h4.x, bflo(w.x), q0);
            q1 = fmaf(h4.y, bfhi(w.x), q1);
            q2 = fmaf(h4.z, bflo(w.y), q2);
            q3 = fmaf(h4.w, bfhi(w.y), q3);
        }
        float acc = (q0+q1) + (q2+q3) + b2[e*H2 + c];
        float y = gelu(acc);
        float s  = red32(y);
        float s2 = red32(y*y);
        float mean2 = s * (1.0f/H2);
        float var2  = s2 * (1.0f/H2) - mean2*mean2;
        hv = (y - mean2) * rsqrtf(var2 + 1e-5f) * g2[e*H2+c] + be2[e*H2+c];
    }

    // ---- 12 residual blocks: weights direct from packed global, zero barriers ----
    for (int tb = 0; tb < NBLK; tb++){
        const float* vA = &vecs[tb*192];
        const uint2* WA = (const uint2*)(rpk + (((size_t)(tb*2+0)*E + e) << 9));
        const uint2* WB = (const uint2*)(rpk + (((size_t)(tb*2+1)*E + e) << 9));
        sh2[m][c] = hv;
        float q0=0.f,q1=0.f,q2=0.f,q3=0.f;
        #pragma unroll
        for (int p2 = 0; p2 < 8; p2++){
            uint2 w = WA[p2*32 + c];
            float4 h4 = *(const float4*)(&sh2[m][p2*4]);
            q0 = fmaf(h4.x, bflo(w.x), q0);
            q1 = fmaf(h4.y, bfhi(w.x), q1);
            q2 = fmaf(h4.z, bflo(w.y), q2);
            q3 = fmaf(h4.w, bfhi(w.y), q3);
        }
        float ya = (q0+q1) + (q2+q3) + vA[c];
        ya = gelu(ya);
        float sa  = red32(ya);
        float sa2 = red32(ya*ya);
        float ma = sa * (1.0f/H2);
        float va = sa2 * (1.0f/H2) - ma*ma;
        float yA = (ya - ma) * rsqrtf(va + 1e-5f) * vA[32+c] + vA[64+c];
        sh3[m][c] = yA;
        q0=0.f; q1=0.f; q2=0.f; q3=0.f;
        #pragma unroll
        for (int p2 = 0; p2 < 8; p2++){
            uint2 w = WB[p2*32 + c];
            float4 h4 = *(const float4*)(&sh3[m][p2*4]);
            q0 = fmaf(h4.x, bflo(w.x), q0);
            q1 = fmaf(h4.y, bfhi(w.x), q1);
            q2 = fmaf(h4.z, bflo(w.y), q2);
            q3 = fmaf(h4.w, bfhi(w.y), q3);
        }
        float yb = (q0+q1) + (q2+q3) + vA[96+c];
        yb = gelu(yb);
        float sb  = red32(yb);
        float sb2 = red32(yb*yb);
        float mb = sb * (1.0f/H2);
        float vb = sb2 * (1.0f/H2) - mb*mb;
        hv += (yb - mb) * rsqrtf(vb + 1e-5f) * vA[128+c] + vA[160+c];
    }

    // ---- out-proj + softmax + p_win ----
    sh2[m][c] = gelu(hv);
    __syncthreads();
    int wave = tid >> 6, lane = tid & 63;
    const float* W = Ow + (size_t)e*32*NOUT;
    for (int rr = wave; rr < 8; rr += 4){
        int orow = perm[t*MT + r0 + rr];
        if (orow < 0) continue;
        float acc = (lane < NOUT) ? Ob[e*NOUT + lane] : -INFINITY;
        #pragma unroll
        for (int k = 0; k < 32; k++){
            float gk = sh2[rr][k];
            if (lane < NOUT) acc = fmaf(gk, W[k*NOUT + lane], acc);
        }
        if (lane < NOUT) out[(size_t)orow*NOUT + lane] = acc;
        float mx = acc;
        #pragma unroll
        for (int o = 32; o > 0; o >>= 1) mx = fmaxf(mx, __shfl_xor(mx, o));
        float pp = (lane < NOUT) ? expf(acc - mx) : 0.0f;
        float sum = pp;
        float pb = (lane < NOUT) ? pp * bins[lane] : 0.0f;
        float sb = pb;
        #pragma unroll
        for (int o = 32; o > 0; o >>= 1){ sum += __shfl_xor(sum, o); sb += __shfl_xor(sb, o); }
        if (lane == 0) out[(size_t)N*NOUT + orow] = sb / sum;
    }
}

extern "C" void kernel_launch(void* const* d_in, const int* in_sizes, int n_in,
                              void* d_out, int out_size, void* d_ws, size_t ws_size,
                              hipStream_t stream){
    const int*   piece_idx = (const int*)d_in[0];
    const int*   side_flag = (const int*)d_in[1];
    const int*   ep_file   = (const int*)d_in[2];
    const float* castle_ms = (const float*)d_in[3];
    const float* fifty_a   = (const float*)d_in[4];
    const int*   desc      = (const int*)d_in[5];
    const float* Wp_w  = (const float*)d_in[6];
    const float* Wp_b  = (const float*)d_in[7];
    const float* Wc_w  = (const float*)d_in[8];
    const float* Wc_b  = (const float*)d_in[9];
    const float* Wep_w = (const float*)d_in[10];
    const float* Wep_b = (const float*)d_in[11];
    const float* Wf_w  = (const float*)d_in[12];
    const float* Wf_b  = (const float*)d_in[13];
    const float* fc1_w = (const float*)d_in[14];
    const float* fc1_b = (const float*)d_in[15];
    const float* ln1_g = (const float*)d_in[16];
    const float* ln1_b = (const float*)d_in[17];
    const float* fc2_w = (const float*)d_in[18];
    const float* fc2_b = (const float*)d_in[19];
    const float* ln2_g = (const float*)d_in[20];
    const float* ln2_b = (const float*)d_in[21];
    const float* blkA_w  = (const float*)d_in[22];
    const float* blkA_b  = (const float*)d_in[23];
    const float* blkA_g  = (const float*)d_in[24];
    const float* blkA_be = (const float*)d_in[25];
    const float* blkB_w  = (const float*)d_in[26];
    const float* blkB_b  = (const float*)d_in[27];
    const float* blkB_g  = (const float*)d_in[28];
    const float* blkB_be = (const float*)d_in[29];
    const float* out_w = (const float*)d_in[30];
    const float* out_b = (const float*)d_in[31];
    const float* bins  = (const float*)d_in[32];

    char* wsp = (char*)d_ws;
    auto alloc = [&](size_t bytes){ void* p = (void*)wsp; wsp += (bytes + 255) & ~(size_t)255; return p; };
    int*            perm    = (int*)            alloc((size_t)(NPAD+128)*4);
    int*            tile_e  = (int*)            alloc((size_t)NTILE*4);
    int4*           garr    = (int4*)           alloc((size_t)GMAX*16);
    int*            ngroups = (int*)            alloc(256);
    unsigned int*   w2pk_g  = (unsigned int*)   alloc((size_t)E*4096*4);
    unsigned int*   rpk     = (unsigned int*)   alloc((size_t)24*E*512*4);
    unsigned short* xs      = (unsigned short*) alloc((size_t)(N+128)*D_IN*2);
    float*          h1p     = (float*)          alloc((size_t)KSPLIT*NROWS*H1*4);

    k_pack<<<2048, 256, 0, stream>>>(fc2_w, blkA_w, blkB_w, w2pk_g, rpk);
    k_prep<<<1 + N, 256, 0, stream>>>(piece_idx, side_flag, ep_file,
                                      castle_ms, fifty_a, desc,
                                      Wp_w, Wp_b, Wc_w, Wc_b,
                                      Wep_w, Wep_b, Wf_w, Wf_b,
                                      xs, perm, tile_e, garr, ngroups);
    k_fc1<<<dim3(GMAX, KSPLIT, 2), 256, 0, stream>>>(garr, ngroups, xs, perm, fc1_w, h1p);
    k_tail<<<NTILE*2, 256, 0, stream>>>(tile_e, perm, h1p, fc1_b, ln1_g, ln1_b,
                                        w2pk_g, fc2_b, ln2_g, ln2_b,
                                        rpk,
                                        blkA_b, blkA_g, blkA_be,
                                        blkB_b, blkB_g, blkB_be,
                                        out_w, out_b, bins, (float*)d_out);
}